// Round 4
// baseline (30270.239 us; speedup 1.0000x reference)
//
#include <hip/hip_runtime.h>
#include <math.h>

#define BB 128
#define TT 512
#define FF 128
#define HH 512
#define NR 2048      // gate rows (4 gates x 512 j, permuted)
#define TC 16        // timesteps per chunk = steps per rec launch
#define HB (HH*BB)   // 65536 floats per h state

// ---------------- prep kernels ----------------

__global__ __launch_bounds__(256) void k_zero(float* __restrict__ p, int n) {
  int i = blockIdx.x * 256 + threadIdx.x;
  if (i < n) p[i] = 0.f;
}

// W[k][col] (col = g*512 + q) -> Wp[k][r], r = (q>>1)*8 + (q&1)*4 + g
__global__ __launch_bounds__(256) void k_rearr_W(const float* __restrict__ src,
                                                 float* __restrict__ dst, int n) {
  int idx = blockIdx.x * 256 + threadIdx.x;
  if (idx >= n) return;
  int k = idx >> 11, col = idx & 2047;
  int q = col & 511, g = col >> 9;
  int r = (q >> 1) * 8 + (q & 1) * 4 + g;
  dst[k * NR + r] = src[idx];
}

// U[k][col] -> Ucp[jb][k][8]  (jb = q>>1; row r = (q&1)*4 + g)
__global__ __launch_bounds__(256) void k_rearr_U(const float* __restrict__ src,
                                                 float* __restrict__ dst) {
  int idx = blockIdx.x * 256 + threadIdx.x;   // over 512*2048
  int k = idx >> 11, col = idx & 2047;
  int q = col & 511, g = col >> 9;
  dst[(size_t)(q >> 1) * 4096 + k * 8 + (q & 1) * 4 + g] = src[idx];
}

// ---------------- projection GEMM ----------------
// xz[tl][r0..r0+128][b] = in_t @ Wp + bp, one t per blockIdx.y.
// MODE 0: input = x[b][t][f] (layer 1, KD=128). MODE 1: input = seq[t][k][b] (KD=512).
template <int MODE, int KD>
__global__ __launch_bounds__(256, 4) void k_proj(const float* __restrict__ in,
                                                 const float* __restrict__ Wp,
                                                 const float* __restrict__ bp,
                                                 float* __restrict__ xz, int t0) {
  __shared__ float Wt[16 * 132];
  __shared__ float Xs[16 * 132];
  int tid = threadIdx.x;
  int r0 = blockIdx.x * 128;
  int tl = blockIdx.y;
  int ty = tid >> 4, tx = tid & 15;
  float acc[8][8];
#pragma unroll
  for (int i = 0; i < 8; ++i)
#pragma unroll
    for (int j = 0; j < 8; ++j) acc[i][j] = 0.f;

  for (int k0 = 0; k0 < KD; k0 += 16) {
    {
      int idx = tid * 8;
      int i = idx >> 7, rr = idx & 127;
      const float* src = Wp + (size_t)(k0 + i) * NR + r0 + rr;
      float4 v0 = *(const float4*)(src);
      float4 v1 = *(const float4*)(src + 4);
      *(float4*)&Wt[i * 132 + rr] = v0;
      *(float4*)&Wt[i * 132 + rr + 4] = v1;
    }
    if (MODE == 1) {
      int idx = tid * 8;
      int i = idx >> 7, bb = idx & 127;
      const float* src = in + (size_t)tl * HB + (size_t)(k0 + i) * BB + bb;
      float4 v0 = *(const float4*)(src);
      float4 v1 = *(const float4*)(src + 4);
      *(float4*)&Xs[i * 132 + bb] = v0;
      *(float4*)&Xs[i * 132 + bb + 4] = v1;
    } else {
      int bb = tid >> 1, half = tid & 1;
      int tg = t0 + tl;
      const float* src = in + (size_t)bb * (TT * FF) + (size_t)tg * FF + k0 + half * 8;
      float4 v0 = *(const float4*)(src);
      float4 v1 = *(const float4*)(src + 4);
#pragma unroll
      for (int q = 0; q < 4; ++q) Xs[(half * 8 + q) * 132 + bb] = (&v0.x)[q];
#pragma unroll
      for (int q = 0; q < 4; ++q) Xs[(half * 8 + 4 + q) * 132 + bb] = (&v1.x)[q];
    }
    __syncthreads();
#pragma unroll
    for (int k = 0; k < 16; ++k) {
      float4 wA = *(const float4*)&Wt[k * 132 + ty * 8];
      float4 wB = *(const float4*)&Wt[k * 132 + ty * 8 + 4];
      float4 xA = *(const float4*)&Xs[k * 132 + tx * 8];
      float4 xB = *(const float4*)&Xs[k * 132 + tx * 8 + 4];
      float w[8] = {wA.x, wA.y, wA.z, wA.w, wB.x, wB.y, wB.z, wB.w};
      float xv[8] = {xA.x, xA.y, xA.z, xA.w, xB.x, xB.y, xB.z, xB.w};
#pragma unroll
      for (int i = 0; i < 8; ++i)
#pragma unroll
        for (int j = 0; j < 8; ++j) acc[i][j] = fmaf(w[i], xv[j], acc[i][j]);
    }
    __syncthreads();
  }
#pragma unroll
  for (int i = 0; i < 8; ++i) {
    float bv = bp[r0 + ty * 8 + i];
    float* dst = xz + ((size_t)tl * NR + r0 + ty * 8 + i) * BB + tx * 8;
    float4 o0 = {acc[i][0] + bv, acc[i][1] + bv, acc[i][2] + bv, acc[i][3] + bv};
    float4 o1 = {acc[i][4] + bv, acc[i][5] + bv, acc[i][6] + bv, acc[i][7] + bv};
    *(float4*)(dst) = o0;
    *(float4*)(dst + 4) = o1;
  }
}

// ---------------- persistent recurrent kernel (TC steps, grid-synced) ----------------
// Grid 256 blocks x 1024 threads (1 block/CU, co-resident).
// Block jb owns gate rows jb*8..jb*8+7. U slice (16 KB) read via wave-uniform
// scalar loads (fits L1/sK$; NO LDS broadcast — dodges the ds_read writeback wall).
// Thread: b = tid&127, kq = tid>>7 (8-way split-K).
// Sync: release fetch_add + RELAXED polls + ONE acquire fence per step.
__global__ __launch_bounds__(1024, 4) void k_rec(const float* __restrict__ Ucp,
                                                 const float* __restrict__ xz,
                                                 const float* __restrict__ hin0,
                                                 float* __restrict__ hchain,
                                                 float* __restrict__ cT,
                                                 int* __restrict__ ctr) {
  __shared__ float red[8192];
  __shared__ float zb[1024];
  int tid = threadIdx.x;
  int b = tid & 127;
  int kq = tid >> 7;
  int jb = blockIdx.x;
  const float* __restrict__ up = Ucp + (size_t)jb * 4096;  // [512 k][8 r]

  float c_reg = 0.f;
  int jl = tid >> 7;  // tail threads (tid<256): jl in {0,1}
  if (tid < 256) c_reg = cT[(jb * 2 + jl) * BB + b];

  for (int s = 0; s < TC; ++s) {
    const float* __restrict__ h = (s == 0) ? hin0 : (hchain + (size_t)(s - 1) * HB);
    const float* __restrict__ hk = h + (size_t)(kq * 64) * BB + b;
    const float* __restrict__ uk = up + kq * 64 * 8;
    float a0 = 0.f, a1 = 0.f, a2 = 0.f, a3 = 0.f;
    float a4 = 0.f, a5 = 0.f, a6 = 0.f, a7 = 0.f;
    for (int kk = 0; kk < 64; kk += 8) {
      float hv[8];
#pragma unroll
      for (int u = 0; u < 8; ++u) hv[u] = hk[(size_t)(kk + u) * BB];
#pragma unroll
      for (int u = 0; u < 8; ++u) {
        const float* uu = uk + (kk + u) * 8;
        a0 = fmaf(hv[u], uu[0], a0); a1 = fmaf(hv[u], uu[1], a1);
        a2 = fmaf(hv[u], uu[2], a2); a3 = fmaf(hv[u], uu[3], a3);
        a4 = fmaf(hv[u], uu[4], a4); a5 = fmaf(hv[u], uu[5], a5);
        a6 = fmaf(hv[u], uu[6], a6); a7 = fmaf(hv[u], uu[7], a7);
      }
    }
    int rb = kq * 1024 + b;
    red[rb + 0 * 128] = a0; red[rb + 1 * 128] = a1;
    red[rb + 2 * 128] = a2; red[rb + 3 * 128] = a3;
    red[rb + 4 * 128] = a4; red[rb + 5 * 128] = a5;
    red[rb + 6 * 128] = a6; red[rb + 7 * 128] = a7;
    __syncthreads();
    {
      int ig = tid >> 7;
      float z = red[ig * 128 + b];
#pragma unroll
      for (int q = 1; q < 8; ++q) z += red[q * 1024 + ig * 128 + b];
      z += xz[((size_t)s * NR + jb * 8 + ig) * BB + b];
      zb[ig * 128 + b] = z;
    }
    __syncthreads();
    if (tid < 256) {
      float z0 = zb[(jl * 4 + 0) * 128 + b];
      float z1 = zb[(jl * 4 + 1) * 128 + b];
      float z2 = zb[(jl * 4 + 2) * 128 + b];
      float z3 = zb[(jl * 4 + 3) * 128 + b];
      float igt = 1.f / (1.f + __expf(-z0));
      float fgt = 1.f / (1.f + __expf(-z1));
      float ggt = tanhf(z2);
      float ogt = 1.f / (1.f + __expf(-z3));
      c_reg = fgt * c_reg + igt * ggt;
      float hn = ogt * tanhf(c_reg);
      float* hout = hchain + (size_t)s * HB;
      __hip_atomic_store(&hout[(jb * 2 + jl) * BB + b], hn,
                         __ATOMIC_RELAXED, __HIP_MEMORY_SCOPE_AGENT);
    }
    __syncthreads();  // all waves drain their stores (vmcnt) before tid0 signals
    if (tid == 0) {
      __hip_atomic_fetch_add(ctr, 1, __ATOMIC_RELEASE, __HIP_MEMORY_SCOPE_AGENT);
      int tgt = 256 * (s + 1);
      while (__hip_atomic_load(ctr, __ATOMIC_RELAXED, __HIP_MEMORY_SCOPE_AGENT) < tgt)
        __builtin_amdgcn_s_sleep(2);
      __builtin_amdgcn_fence(__ATOMIC_ACQUIRE, "agent");  // one inv per step
    }
    __syncthreads();
  }
  if (tid < 256) cT[(jb * 2 + jl) * BB + b] = c_reg;
}

// ---------------- dense + softmax ----------------
__global__ __launch_bounds__(64) void k_dense(const float* __restrict__ h2,
                                              const float* __restrict__ Wd,
                                              const float* __restrict__ bd,
                                              float* __restrict__ out) {
  int b = blockIdx.x * 64 + threadIdx.x;
  float acc[10];
#pragma unroll
  for (int c = 0; c < 10; ++c) acc[c] = bd[c];
  for (int k = 0; k < HH; ++k) {
    float hv = h2[k * BB + b];
#pragma unroll
    for (int c = 0; c < 10; ++c) acc[c] = fmaf(hv, Wd[k * 10 + c], acc[c]);
  }
  float m = acc[0];
#pragma unroll
  for (int c = 1; c < 10; ++c) m = fmaxf(m, acc[c]);
  float s = 0.f;
#pragma unroll
  for (int c = 0; c < 10; ++c) { acc[c] = __expf(acc[c] - m); s += acc[c]; }
  float inv = 1.f / s;
#pragma unroll
  for (int c = 0; c < 10; ++c) out[b * 10 + c] = acc[c] * inv;
}

// ---------------- host ----------------
extern "C" void kernel_launch(void* const* d_in, const int* in_sizes, int n_in,
                              void* d_out, int out_size, void* d_ws, size_t ws_size,
                              hipStream_t stream) {
  const float* x  = (const float*)d_in[0];
  const float* W1 = (const float*)d_in[1];
  const float* U1 = (const float*)d_in[2];
  const float* b1 = (const float*)d_in[3];
  const float* W2 = (const float*)d_in[4];
  const float* U2 = (const float*)d_in[5];
  const float* b2 = (const float*)d_in[6];
  const float* Wd = (const float*)d_in[7];
  const float* bd = (const float*)d_in[8];
  float* out = (float*)d_out;

  float* ws  = (float*)d_ws;
  float* seq = ws;                               // [512][512][128]  33,554,432
  float* xz  = seq + (size_t)TT * HB;            // [16][2048][128]   4,194,304
  float* Ucp = xz + (size_t)TC * NR * BB;        // [256][512][8]     1,048,576
  float* Wp1 = Ucp + (size_t)256 * 4096;         //   262,144
  float* Wp2 = Wp1 + (size_t)FF * NR;            // 1,048,576
  float* bp1 = Wp2 + (size_t)HH * NR;            //     2,048
  float* bp2 = bp1 + NR;                         //     2,048
  float* hR  = bp2 + NR;                         // [16][65536]       1,048,576
  float* cT  = hR + (size_t)TC * HB;             //    65,536
  int*   ctrs = (int*)(cT + HB);                 //       128 ints
  // total ~41.2M floats ~165 MB (proven size in R3)

  // prep
  k_zero<<<(HB + 255) / 256, 256, 0, stream>>>(cT, HB);
  k_zero<<<(HB + 255) / 256, 256, 0, stream>>>(hR, HB);          // hR[0] = layer-1 h0 = 0
  k_zero<<<1, 256, 0, stream>>>((float*)ctrs, 128);
  k_rearr_W<<<(FF * NR) / 256, 256, 0, stream>>>(W1, Wp1, FF * NR);
  k_rearr_W<<<(HH * NR) / 256, 256, 0, stream>>>(W2, Wp2, HH * NR);
  k_rearr_W<<<NR / 256, 256, 0, stream>>>(b1, bp1, NR);
  k_rearr_W<<<NR / 256, 256, 0, stream>>>(b2, bp2, NR);
  k_rearr_U<<<(HH * NR) / 256, 256, 0, stream>>>(U1, Ucp);

  // layer 1: h chain lives in seq[t] (globally fresh slots)
  for (int c = 0; c < TT / TC; ++c) {
    int t0 = c * TC;
    k_proj<0, FF><<<dim3(NR / 128, TC), 256, 0, stream>>>(x, Wp1, bp1, xz, t0);
    const float* hin0 = (c == 0) ? hR : (seq + (size_t)(t0 - 1) * HB);
    k_rec<<<256, 1024, 0, stream>>>(Ucp, xz, hin0, seq + (size_t)t0 * HB, cT, &ctrs[c]);
  }
  // swap U buffer to layer 2
  k_rearr_U<<<(HH * NR) / 256, 256, 0, stream>>>(U2, Ucp);
  // layer 2: h chain in hR ring (fresh slot per step within a launch)
  for (int c = 0; c < TT / TC; ++c) {
    int t0 = c * TC;
    k_proj<1, HH><<<dim3(NR / 128, TC), 256, 0, stream>>>(seq + (size_t)t0 * HB,
                                                          Wp2, bp2, xz, t0);
    const float* hin0 = (c == 0) ? (seq + (size_t)(TT - 1) * HB)
                                 : (hR + (size_t)(TC - 1) * HB);
    k_rec<<<256, 1024, 0, stream>>>(Ucp, xz, hin0, hR, cT, &ctrs[32 + c]);
  }
  k_dense<<<BB / 64, 64, 0, stream>>>(hR + (size_t)(TC - 1) * HB, Wd, bd, out);
}

// Round 5
// 14316.541 us; speedup vs baseline: 2.1144x; 2.1144x over previous
//
#include <hip/hip_runtime.h>
#include <math.h>

#define BB 128
#define TT 512
#define FF 128
#define HH 512
#define NR 2048      // gate rows, row = 4*j + g
#define TC 16        // timesteps per rec launch
#define HB (HH*BB)   // 65536 floats per h state

// ---------------- prep kernels ----------------

__global__ __launch_bounds__(256) void k_zero(float* __restrict__ p, int n) {
  int i = blockIdx.x * 256 + threadIdx.x;
  if (i < n) p[i] = 0.f;
}

// W[k][col] (col = g*512 + j) -> Wp[k][4j+g]; also used for bias (n=2048)
__global__ __launch_bounds__(256) void k_rearr_W(const float* __restrict__ src,
                                                 float* __restrict__ dst, int n) {
  int idx = blockIdx.x * 256 + threadIdx.x;
  if (idx >= n) return;
  int k = idx >> 11, col = idx & 2047;
  int j = col & 511, g = col >> 9;
  dst[k * NR + j * 4 + g] = src[idx];
}

// U[k][col] -> Ucp[jb2][k][ (j&3)*4 + g ]   (jb2 = j>>2; 128 slices of [512][16])
__global__ __launch_bounds__(256) void k_rearr_U(const float* __restrict__ src,
                                                 float* __restrict__ dst) {
  int idx = blockIdx.x * 256 + threadIdx.x;   // over 512*2048
  int k = idx >> 11, col = idx & 2047;
  int j = col & 511, g = col >> 9;
  dst[(size_t)(j >> 2) * 8192 + k * 16 + (j & 3) * 4 + g] = src[idx];
}

// ---------------- projection GEMM ----------------
// xz[tl][r0..r0+128][b] = in_t @ Wp + bp, one t per blockIdx.y.
// MODE 0: input = x[b][t][f] (layer 1, KD=128). MODE 1: input = seq[t][k][b] (KD=512).
template <int MODE, int KD>
__global__ __launch_bounds__(256, 4) void k_proj(const float* __restrict__ in,
                                                 const float* __restrict__ Wp,
                                                 const float* __restrict__ bp,
                                                 float* __restrict__ xz, int t0) {
  __shared__ float Wt[16 * 132];
  __shared__ float Xs[16 * 132];
  int tid = threadIdx.x;
  int r0 = blockIdx.x * 128;
  int tl = blockIdx.y;
  int ty = tid >> 4, tx = tid & 15;
  float acc[8][8];
#pragma unroll
  for (int i = 0; i < 8; ++i)
#pragma unroll
    for (int j = 0; j < 8; ++j) acc[i][j] = 0.f;

  for (int k0 = 0; k0 < KD; k0 += 16) {
    {
      int idx = tid * 8;
      int i = idx >> 7, rr = idx & 127;
      const float* src = Wp + (size_t)(k0 + i) * NR + r0 + rr;
      float4 v0 = *(const float4*)(src);
      float4 v1 = *(const float4*)(src + 4);
      *(float4*)&Wt[i * 132 + rr] = v0;
      *(float4*)&Wt[i * 132 + rr + 4] = v1;
    }
    if (MODE == 1) {
      int idx = tid * 8;
      int i = idx >> 7, bb = idx & 127;
      const float* src = in + (size_t)tl * HB + (size_t)(k0 + i) * BB + bb;
      float4 v0 = *(const float4*)(src);
      float4 v1 = *(const float4*)(src + 4);
      *(float4*)&Xs[i * 132 + bb] = v0;
      *(float4*)&Xs[i * 132 + bb + 4] = v1;
    } else {
      int bb = tid >> 1, half = tid & 1;
      int tg = t0 + tl;
      const float* src = in + (size_t)bb * (TT * FF) + (size_t)tg * FF + k0 + half * 8;
      float4 v0 = *(const float4*)(src);
      float4 v1 = *(const float4*)(src + 4);
#pragma unroll
      for (int q = 0; q < 4; ++q) Xs[(half * 8 + q) * 132 + bb] = (&v0.x)[q];
#pragma unroll
      for (int q = 0; q < 4; ++q) Xs[(half * 8 + 4 + q) * 132 + bb] = (&v1.x)[q];
    }
    __syncthreads();
#pragma unroll
    for (int k = 0; k < 16; ++k) {
      float4 wA = *(const float4*)&Wt[k * 132 + ty * 8];
      float4 wB = *(const float4*)&Wt[k * 132 + ty * 8 + 4];
      float4 xA = *(const float4*)&Xs[k * 132 + tx * 8];
      float4 xB = *(const float4*)&Xs[k * 132 + tx * 8 + 4];
      float w[8] = {wA.x, wA.y, wA.z, wA.w, wB.x, wB.y, wB.z, wB.w};
      float xv[8] = {xA.x, xA.y, xA.z, xA.w, xB.x, xB.y, xB.z, xB.w};
#pragma unroll
      for (int i = 0; i < 8; ++i)
#pragma unroll
        for (int j = 0; j < 8; ++j) acc[i][j] = fmaf(w[i], xv[j], acc[i][j]);
    }
    __syncthreads();
  }
#pragma unroll
  for (int i = 0; i < 8; ++i) {
    float bv = bp[r0 + ty * 8 + i];
    float* dst = xz + ((size_t)tl * NR + r0 + ty * 8 + i) * BB + tx * 8;
    float4 o0 = {acc[i][0] + bv, acc[i][1] + bv, acc[i][2] + bv, acc[i][3] + bv};
    float4 o1 = {acc[i][4] + bv, acc[i][5] + bv, acc[i][6] + bv, acc[i][7] + bv};
    *(float4*)(dst) = o0;
    *(float4*)(dst + 4) = o1;
  }
}

// ---------------- persistent recurrent kernel (TC steps, grid-synced) ----------------
// Grid 256 x 1024 (1 block/CU). Block = (jb2 = bx>>1) owns gate rows jb2*16..+15
// (j = jb2*4..+3), (bh = bx&1) owns batch half. NO fences: h published with
// relaxed agent atomic stores (write-through L3) and read with relaxed agent
// atomic loads (cache-bypass -> always fresh); U/xz stay warm in L1/L2/sK$.
// Thread: b = tid&63, kq = tid>>6 (16-way split-K, 32 k each; kq == wave id).
__global__ __launch_bounds__(1024, 4) void k_rec(const float* __restrict__ Ucp,
                                                 const float* __restrict__ xz,
                                                 const float* __restrict__ hin0,
                                                 float* __restrict__ hchain,
                                                 float* __restrict__ cT,
                                                 int* __restrict__ ctr) {
  __shared__ float red[16 * 1024];  // [kq][r][b64]
  __shared__ float zs[1024];        // [r][b64]
  int tid = threadIdx.x;
  int b = tid & 63;
  int kq = tid >> 6;
  int jb2 = blockIdx.x >> 1;
  int bh = blockIdx.x & 1;
  int bg = bh * 64 + b;
  int kqu = __builtin_amdgcn_readfirstlane(kq);
  const float* __restrict__ uk = Ucp + (size_t)jb2 * 8192 + kqu * 32 * 16;  // [32 k][16 r]

  float c_reg = 0.f;
  int jj = tid >> 6;                 // tail threads (tid<256): jj 0..3
  int jg = jb2 * 4 + jj;
  if (tid < 256) c_reg = cT[jg * BB + bg];

  for (int s = 0; s < TC; ++s) {
    const float* __restrict__ h = (s == 0) ? hin0 : (hchain + (size_t)(s - 1) * HB);
    const float* __restrict__ hb = h + bg;
    float acc[16];
#pragma unroll
    for (int r = 0; r < 16; ++r) acc[r] = 0.f;
    for (int kk = 0; kk < 32; kk += 8) {
      float hv[8];
#pragma unroll
      for (int u = 0; u < 8; ++u)
        hv[u] = __hip_atomic_load(&hb[(kqu * 32 + kk + u) * BB],
                                  __ATOMIC_RELAXED, __HIP_MEMORY_SCOPE_AGENT);
#pragma unroll
      for (int u = 0; u < 8; ++u) {
        const float* uu = uk + (kk + u) * 16;
#pragma unroll
        for (int r = 0; r < 16; ++r) acc[r] = fmaf(hv[u], uu[r], acc[r]);
      }
    }
#pragma unroll
    for (int r = 0; r < 16; ++r) red[kq * 1024 + r * 64 + b] = acc[r];
    __syncthreads();
    {
      int r2 = tid >> 6;  // reuse wave id as row id
      float z = red[r2 * 64 + b];
#pragma unroll
      for (int q = 1; q < 16; ++q) z += red[q * 1024 + r2 * 64 + b];
      z += xz[((size_t)s * NR + jb2 * 16 + r2) * BB + bg];
      zs[r2 * 64 + b] = z;
    }
    __syncthreads();
    if (tid < 256) {
      float z0 = zs[(jj * 4 + 0) * 64 + b];
      float z1 = zs[(jj * 4 + 1) * 64 + b];
      float z2 = zs[(jj * 4 + 2) * 64 + b];
      float z3 = zs[(jj * 4 + 3) * 64 + b];
      float igt = 1.f / (1.f + __expf(-z0));
      float fgt = 1.f / (1.f + __expf(-z1));
      float ggt = tanhf(z2);
      float ogt = 1.f / (1.f + __expf(-z3));
      c_reg = fgt * c_reg + igt * ggt;
      float hn = ogt * tanhf(c_reg);
      __hip_atomic_store(&hchain[(size_t)s * HB + jg * BB + bg], hn,
                         __ATOMIC_RELAXED, __HIP_MEMORY_SCOPE_AGENT);
    }
    __syncthreads();  // waves 0-3 drain h stores (vmcnt0) before wave 0 signals
    if (tid == 0) {
      __hip_atomic_fetch_add(ctr, 1, __ATOMIC_RELAXED, __HIP_MEMORY_SCOPE_AGENT);
      int tgt = 256 * (s + 1);
      while (__hip_atomic_load(ctr, __ATOMIC_RELAXED, __HIP_MEMORY_SCOPE_AGENT) < tgt)
        __builtin_amdgcn_s_sleep(1);
    }
    __syncthreads();
  }
  if (tid < 256) cT[jg * BB + bg] = c_reg;
}

// ---------------- dense + softmax ----------------
__global__ __launch_bounds__(64) void k_dense(const float* __restrict__ h2,
                                              const float* __restrict__ Wd,
                                              const float* __restrict__ bd,
                                              float* __restrict__ out) {
  int b = blockIdx.x * 64 + threadIdx.x;
  float acc[10];
#pragma unroll
  for (int c = 0; c < 10; ++c) acc[c] = bd[c];
  for (int k = 0; k < HH; ++k) {
    float hv = h2[k * BB + b];
#pragma unroll
    for (int c = 0; c < 10; ++c) acc[c] = fmaf(hv, Wd[k * 10 + c], acc[c]);
  }
  float m = acc[0];
#pragma unroll
  for (int c = 1; c < 10; ++c) m = fmaxf(m, acc[c]);
  float s = 0.f;
#pragma unroll
  for (int c = 0; c < 10; ++c) { acc[c] = __expf(acc[c] - m); s += acc[c]; }
  float inv = 1.f / s;
#pragma unroll
  for (int c = 0; c < 10; ++c) out[b * 10 + c] = acc[c] * inv;
}

// ---------------- host ----------------
extern "C" void kernel_launch(void* const* d_in, const int* in_sizes, int n_in,
                              void* d_out, int out_size, void* d_ws, size_t ws_size,
                              hipStream_t stream) {
  const float* x  = (const float*)d_in[0];
  const float* W1 = (const float*)d_in[1];
  const float* U1 = (const float*)d_in[2];
  const float* b1 = (const float*)d_in[3];
  const float* W2 = (const float*)d_in[4];
  const float* U2 = (const float*)d_in[5];
  const float* b2 = (const float*)d_in[6];
  const float* Wd = (const float*)d_in[7];
  const float* bd = (const float*)d_in[8];
  float* out = (float*)d_out;

  float* ws  = (float*)d_ws;
  float* seq = ws;                               // [512][512][128]  33,554,432
  float* xz  = seq + (size_t)TT * HB;            // [16][2048][128]   4,194,304
  float* Ucp = xz + (size_t)TC * NR * BB;        // [128][512][16]    1,048,576
  float* Wp1 = Ucp + (size_t)HH * NR;            //   262,144
  float* Wp2 = Wp1 + (size_t)FF * NR;            // 1,048,576
  float* bp1 = Wp2 + (size_t)HH * NR;            //     2,048
  float* bp2 = bp1 + NR;                         //     2,048
  float* hR  = bp2 + NR;                         // [16][65536]       1,048,576
  float* cT  = hR + (size_t)TC * HB;             //    65,536
  int*   ctrs = (int*)(cT + HB);                 //       128 ints
  // total ~41.2M floats ~165 MB (same footprint as R3/R4)

  // prep
  k_zero<<<(HB + 255) / 256, 256, 0, stream>>>(cT, HB);
  k_zero<<<(HB + 255) / 256, 256, 0, stream>>>(hR, HB);          // hR[0] = layer-1 h0 = 0
  k_zero<<<1, 256, 0, stream>>>((float*)ctrs, 128);
  k_rearr_W<<<(FF * NR) / 256, 256, 0, stream>>>(W1, Wp1, FF * NR);
  k_rearr_W<<<(HH * NR) / 256, 256, 0, stream>>>(W2, Wp2, HH * NR);
  k_rearr_W<<<NR / 256, 256, 0, stream>>>(b1, bp1, NR);
  k_rearr_W<<<NR / 256, 256, 0, stream>>>(b2, bp2, NR);
  k_rearr_U<<<(HH * NR) / 256, 256, 0, stream>>>(U1, Ucp);

  // layer 1: h chain lives in seq[t] (globally fresh slots)
  for (int c = 0; c < TT / TC; ++c) {
    int t0 = c * TC;
    k_proj<0, FF><<<dim3(NR / 128, TC), 256, 0, stream>>>(x, Wp1, bp1, xz, t0);
    const float* hin0 = (c == 0) ? hR : (seq + (size_t)(t0 - 1) * HB);
    k_rec<<<256, 1024, 0, stream>>>(Ucp, xz, hin0, seq + (size_t)t0 * HB, cT, &ctrs[c]);
  }
  // swap U buffer to layer 2
  k_rearr_U<<<(HH * NR) / 256, 256, 0, stream>>>(U2, Ucp);
  // layer 2: h chain in hR ring (fresh slot per step within a launch;
  // cross-launch reuse safe because h reads bypass L1/L2)
  for (int c = 0; c < TT / TC; ++c) {
    int t0 = c * TC;
    k_proj<1, HH><<<dim3(NR / 128, TC), 256, 0, stream>>>(seq + (size_t)t0 * HB,
                                                          Wp2, bp2, xz, t0);
    const float* hin0 = (c == 0) ? (seq + (size_t)(TT - 1) * HB)
                                 : (hR + (size_t)(TC - 1) * HB);
    k_rec<<<256, 1024, 0, stream>>>(Ucp, xz, hin0, hR, cT, &ctrs[32 + c]);
  }
  k_dense<<<BB / 64, 64, 0, stream>>>(hR + (size_t)(TC - 1) * HB, Wd, bd, out);
}

// Round 6
// 11552.589 us; speedup vs baseline: 2.6202x; 1.2392x over previous
//
#include <hip/hip_runtime.h>
#include <math.h>

#define BB 128
#define TT 512
#define FF 128
#define HH 512
#define NR 2048      // gate rows, row = 4*j + g
#define TC 16        // timesteps per rec launch
#define HB (HH*BB)   // 65536 floats per h state

// ---------------- prep kernels ----------------

__global__ __launch_bounds__(256) void k_zero(float* __restrict__ p, int n) {
  int i = blockIdx.x * 256 + threadIdx.x;
  if (i < n) p[i] = 0.f;
}

// W[k][col] (col = g*512 + j) -> Wp[k][4j+g]; also used for bias (n=2048)
__global__ __launch_bounds__(256) void k_rearr_W(const float* __restrict__ src,
                                                 float* __restrict__ dst, int n) {
  int idx = blockIdx.x * 256 + threadIdx.x;
  if (idx >= n) return;
  int k = idx >> 11, col = idx & 2047;
  int j = col & 511, g = col >> 9;
  dst[k * NR + j * 4 + g] = src[idx];
}

// U[k][col] -> Ucp[jb2][k][ (j&3)*4 + g ]   (jb2 = j>>2; 128 slices of [512][16])
__global__ __launch_bounds__(256) void k_rearr_U(const float* __restrict__ src,
                                                 float* __restrict__ dst) {
  int idx = blockIdx.x * 256 + threadIdx.x;   // over 512*2048
  int k = idx >> 11, col = idx & 2047;
  int j = col & 511, g = col >> 9;
  dst[(size_t)(j >> 2) * 8192 + k * 16 + (j & 3) * 4 + g] = src[idx];
}

// ---------------- projection GEMM ----------------
// xz[tl][r0..r0+128][b] = in_t @ Wp + bp, one t per blockIdx.y.
// MODE 0: input = x[b][t][f] (layer 1, KD=128). MODE 1: input = seq[t][k][b] (KD=512).
template <int MODE, int KD>
__global__ __launch_bounds__(256, 4) void k_proj(const float* __restrict__ in,
                                                 const float* __restrict__ Wp,
                                                 const float* __restrict__ bp,
                                                 float* __restrict__ xz, int t0) {
  __shared__ float Wt[16 * 132];
  __shared__ float Xs[16 * 132];
  int tid = threadIdx.x;
  int r0 = blockIdx.x * 128;
  int tl = blockIdx.y;
  int ty = tid >> 4, tx = tid & 15;
  float acc[8][8];
#pragma unroll
  for (int i = 0; i < 8; ++i)
#pragma unroll
    for (int j = 0; j < 8; ++j) acc[i][j] = 0.f;

  for (int k0 = 0; k0 < KD; k0 += 16) {
    {
      int idx = tid * 8;
      int i = idx >> 7, rr = idx & 127;
      const float* src = Wp + (size_t)(k0 + i) * NR + r0 + rr;
      float4 v0 = *(const float4*)(src);
      float4 v1 = *(const float4*)(src + 4);
      *(float4*)&Wt[i * 132 + rr] = v0;
      *(float4*)&Wt[i * 132 + rr + 4] = v1;
    }
    if (MODE == 1) {
      int idx = tid * 8;
      int i = idx >> 7, bb = idx & 127;
      const float* src = in + (size_t)tl * HB + (size_t)(k0 + i) * BB + bb;
      float4 v0 = *(const float4*)(src);
      float4 v1 = *(const float4*)(src + 4);
      *(float4*)&Xs[i * 132 + bb] = v0;
      *(float4*)&Xs[i * 132 + bb + 4] = v1;
    } else {
      int bb = tid >> 1, half = tid & 1;
      int tg = t0 + tl;
      const float* src = in + (size_t)bb * (TT * FF) + (size_t)tg * FF + k0 + half * 8;
      float4 v0 = *(const float4*)(src);
      float4 v1 = *(const float4*)(src + 4);
#pragma unroll
      for (int q = 0; q < 4; ++q) Xs[(half * 8 + q) * 132 + bb] = (&v0.x)[q];
#pragma unroll
      for (int q = 0; q < 4; ++q) Xs[(half * 8 + 4 + q) * 132 + bb] = (&v1.x)[q];
    }
    __syncthreads();
#pragma unroll
    for (int k = 0; k < 16; ++k) {
      float4 wA = *(const float4*)&Wt[k * 132 + ty * 8];
      float4 wB = *(const float4*)&Wt[k * 132 + ty * 8 + 4];
      float4 xA = *(const float4*)&Xs[k * 132 + tx * 8];
      float4 xB = *(const float4*)&Xs[k * 132 + tx * 8 + 4];
      float w[8] = {wA.x, wA.y, wA.z, wA.w, wB.x, wB.y, wB.z, wB.w};
      float xv[8] = {xA.x, xA.y, xA.z, xA.w, xB.x, xB.y, xB.z, xB.w};
#pragma unroll
      for (int i = 0; i < 8; ++i)
#pragma unroll
        for (int j = 0; j < 8; ++j) acc[i][j] = fmaf(w[i], xv[j], acc[i][j]);
    }
    __syncthreads();
  }
#pragma unroll
  for (int i = 0; i < 8; ++i) {
    float bv = bp[r0 + ty * 8 + i];
    float* dst = xz + ((size_t)tl * NR + r0 + ty * 8 + i) * BB + tx * 8;
    float4 o0 = {acc[i][0] + bv, acc[i][1] + bv, acc[i][2] + bv, acc[i][3] + bv};
    float4 o1 = {acc[i][4] + bv, acc[i][5] + bv, acc[i][6] + bv, acc[i][7] + bv};
    *(float4*)(dst) = o0;
    *(float4*)(dst + 4) = o1;
  }
}

// ---------------- persistent recurrent kernel (TC steps, dataflow-synced) ----------------
// Grid 256 x 1024 (1 block/CU). Block bx = jb2*2+bh: jb2 owns gate rows
// jb2*16..+15 (j = jb2*4..+3), bh owns batch half. NO global barrier:
// per-block flags hold the producer's completed-step count (monotone).
// Wave kq consumes h rows k in [32kq, 32kq+32) -> produced by blocks
// jb2p = 8kq..8kq+7 (same bh); it polls exactly those 8 flags.
// h published via relaxed agent atomic stores (write-through L3, drained by
// the pre-flag __syncthreads vmcnt(0)); consumed via relaxed agent atomic
// loads (bypass stale L1/L2). U/xz stay warm in caches. Flags use >= targets
// (replay-safe, cross-launch monotone via `base`).
__global__ __launch_bounds__(1024, 4) void k_rec(const float* __restrict__ Ucp,
                                                 const float* __restrict__ xz,
                                                 const float* __restrict__ hin0,
                                                 float* __restrict__ hchain,
                                                 float* __restrict__ cT,
                                                 int* __restrict__ flags,
                                                 int base) {
  __shared__ float red[16 * 1024];  // [kq][r][b64]
  __shared__ float zs[1024];        // [r][b64]
  int tid = threadIdx.x;
  int b = tid & 63;
  int kq = tid >> 6;
  int jb2 = blockIdx.x >> 1;
  int bh = blockIdx.x & 1;
  int bg = bh * 64 + b;
  int kqu = __builtin_amdgcn_readfirstlane(kq);
  const float* __restrict__ uk = Ucp + (size_t)jb2 * 8192 + kqu * 32 * 16;  // [32 k][16 r]
  int fidx = ((kqu * 8 + (b & 7)) << 1) | bh;   // this wave's producer flag (lane-cycled)

  float c_reg = 0.f;
  int jj = tid >> 6;                 // tail threads (tid<256): jj 0..3
  int jg = jb2 * 4 + jj;
  if (tid < 256) c_reg = cT[jg * BB + bg];

  for (int s = 0; s < TC; ++s) {
    // xz prefetch: independent of h -> issue before the poll, consumed post-barrier
    float xzv = xz[((size_t)s * NR + jb2 * 16 + kq) * BB + bg];
    // dataflow wait: my 8 producers must have completed `base+s` steps
    {
      int tgt = base + s;
      while (true) {
        int f = __hip_atomic_load(&flags[fidx], __ATOMIC_RELAXED, __HIP_MEMORY_SCOPE_AGENT);
        if (__all(f >= tgt)) break;
        __builtin_amdgcn_s_sleep(1);
      }
    }
    const float* __restrict__ h = (s == 0) ? hin0 : (hchain + (size_t)(s - 1) * HB);
    const float* __restrict__ hb = h + bg;
    float acc[16];
#pragma unroll
    for (int r = 0; r < 16; ++r) acc[r] = 0.f;
    int kbase = kqu * 32;
    for (int kk = 0; kk < 32; kk += 16) {
      float hv[16];
#pragma unroll
      for (int u = 0; u < 16; ++u)
        hv[u] = __hip_atomic_load(&hb[(kbase + kk + u) * BB],
                                  __ATOMIC_RELAXED, __HIP_MEMORY_SCOPE_AGENT);
#pragma unroll
      for (int u = 0; u < 16; ++u) {
        const float* uu = uk + (kk + u) * 16;
#pragma unroll
        for (int r = 0; r < 16; ++r) acc[r] = fmaf(hv[u], uu[r], acc[r]);
      }
    }
#pragma unroll
    for (int r = 0; r < 16; ++r) red[kq * 1024 + r * 64 + b] = acc[r];
    __syncthreads();
    {
      int r2 = kq;  // wave id doubles as row id
      float z = red[r2 * 64 + b];
#pragma unroll
      for (int q = 1; q < 16; ++q) z += red[q * 1024 + r2 * 64 + b];
      zs[r2 * 64 + b] = z + xzv;
    }
    __syncthreads();
    if (tid < 256) {
      float z0 = zs[(jj * 4 + 0) * 64 + b];
      float z1 = zs[(jj * 4 + 1) * 64 + b];
      float z2 = zs[(jj * 4 + 2) * 64 + b];
      float z3 = zs[(jj * 4 + 3) * 64 + b];
      float igt = 1.f / (1.f + __expf(-z0));
      float fgt = 1.f / (1.f + __expf(-z1));
      float ggt = tanhf(z2);
      float ogt = 1.f / (1.f + __expf(-z3));
      c_reg = fgt * c_reg + igt * ggt;
      float hn = ogt * tanhf(c_reg);
      __hip_atomic_store(&hchain[(size_t)s * HB + jg * BB + bg], hn,
                         __ATOMIC_RELAXED, __HIP_MEMORY_SCOPE_AGENT);
    }
    __syncthreads();  // drains waves 0-3 h stores (vmcnt0) before the flag
    if (tid == 0)
      __hip_atomic_store(&flags[blockIdx.x], base + s + 1,
                         __ATOMIC_RELAXED, __HIP_MEMORY_SCOPE_AGENT);
  }
  if (tid < 256) cT[jg * BB + bg] = c_reg;
}

// ---------------- dense + softmax ----------------
__global__ __launch_bounds__(64) void k_dense(const float* __restrict__ h2,
                                              const float* __restrict__ Wd,
                                              const float* __restrict__ bd,
                                              float* __restrict__ out) {
  int b = blockIdx.x * 64 + threadIdx.x;
  float acc[10];
#pragma unroll
  for (int c = 0; c < 10; ++c) acc[c] = bd[c];
  for (int k = 0; k < HH; ++k) {
    float hv = h2[k * BB + b];
#pragma unroll
    for (int c = 0; c < 10; ++c) acc[c] = fmaf(hv, Wd[k * 10 + c], acc[c]);
  }
  float m = acc[0];
#pragma unroll
  for (int c = 1; c < 10; ++c) m = fmaxf(m, acc[c]);
  float s = 0.f;
#pragma unroll
  for (int c = 0; c < 10; ++c) { acc[c] = __expf(acc[c] - m); s += acc[c]; }
  float inv = 1.f / s;
#pragma unroll
  for (int c = 0; c < 10; ++c) out[b * 10 + c] = acc[c] * inv;
}

// ---------------- host ----------------
extern "C" void kernel_launch(void* const* d_in, const int* in_sizes, int n_in,
                              void* d_out, int out_size, void* d_ws, size_t ws_size,
                              hipStream_t stream) {
  const float* x  = (const float*)d_in[0];
  const float* W1 = (const float*)d_in[1];
  const float* U1 = (const float*)d_in[2];
  const float* b1 = (const float*)d_in[3];
  const float* W2 = (const float*)d_in[4];
  const float* U2 = (const float*)d_in[5];
  const float* b2 = (const float*)d_in[6];
  const float* Wd = (const float*)d_in[7];
  const float* bd = (const float*)d_in[8];
  float* out = (float*)d_out;

  float* ws  = (float*)d_ws;
  float* seq = ws;                               // [512][512][128]  33,554,432
  float* xz  = seq + (size_t)TT * HB;            // [16][2048][128]   4,194,304
  float* Ucp = xz + (size_t)TC * NR * BB;        // [128][512][16]    1,048,576
  float* Wp1 = Ucp + (size_t)HH * NR;            //   262,144
  float* Wp2 = Wp1 + (size_t)FF * NR;            // 1,048,576
  float* bp1 = Wp2 + (size_t)HH * NR;            //     2,048
  float* bp2 = bp1 + NR;                         //     2,048
  float* hR  = bp2 + NR;                         // [16][65536]       1,048,576
  float* cT  = hR + (size_t)TC * HB;             //    65,536
  int*   flags = (int*)(cT + HB);                //       256 ints
  // total ~41.2M floats ~165 MB (same footprint as R5)

  // prep
  k_zero<<<(HB + 255) / 256, 256, 0, stream>>>(cT, HB);
  k_zero<<<(HB + 255) / 256, 256, 0, stream>>>(hR, HB);          // hR[0] = layer-1 h0 = 0
  k_zero<<<1, 256, 0, stream>>>((float*)flags, 256);
  k_rearr_W<<<(FF * NR) / 256, 256, 0, stream>>>(W1, Wp1, FF * NR);
  k_rearr_W<<<(HH * NR) / 256, 256, 0, stream>>>(W2, Wp2, HH * NR);
  k_rearr_W<<<NR / 256, 256, 0, stream>>>(b1, bp1, NR);
  k_rearr_W<<<NR / 256, 256, 0, stream>>>(b2, bp2, NR);
  k_rearr_U<<<(HH * NR) / 256, 256, 0, stream>>>(U1, Ucp);

  // layer 1: h chain lives in seq[t] (globally fresh slots)
  for (int c = 0; c < TT / TC; ++c) {
    int t0 = c * TC;
    k_proj<0, FF><<<dim3(NR / 128, TC), 256, 0, stream>>>(x, Wp1, bp1, xz, t0);
    const float* hin0 = (c == 0) ? hR : (seq + (size_t)(t0 - 1) * HB);
    k_rec<<<256, 1024, 0, stream>>>(Ucp, xz, hin0, seq + (size_t)t0 * HB, cT,
                                    flags, t0);
  }
  // swap U buffer to layer 2
  k_rearr_U<<<(HH * NR) / 256, 256, 0, stream>>>(U2, Ucp);
  // layer 2: h chain in hR ring (fresh slot per step within a launch;
  // cross-launch reuse safe because h reads bypass L1/L2)
  for (int c = 0; c < TT / TC; ++c) {
    int t0 = c * TC;
    k_proj<1, HH><<<dim3(NR / 128, TC), 256, 0, stream>>>(seq + (size_t)t0 * HB,
                                                          Wp2, bp2, xz, t0);
    const float* hin0 = (c == 0) ? (seq + (size_t)(TT - 1) * HB)
                                 : (hR + (size_t)(TC - 1) * HB);
    k_rec<<<256, 1024, 0, stream>>>(Ucp, xz, hin0, hR, cT, flags, TT + t0);
  }
  k_dense<<<BB / 64, 64, 0, stream>>>(hR + (size_t)(TC - 1) * HB, Wd, bd, out);
}

// Round 7
// 9948.579 us; speedup vs baseline: 3.0427x; 1.1612x over previous
//
#include <hip/hip_runtime.h>
#include <math.h>

#define BB 128
#define TT 512
#define FF 128
#define HH 512
#define NR 2048      // gate rows, row = 4*j + g
#define TC 16        // timesteps per rec launch
#define HB (HH*BB)   // 65536 floats per h state
#define FLS 16       // flag stride (ints) -> one flag per 64B line

// ---------------- prep kernels ----------------

__global__ __launch_bounds__(256) void k_zero(float* __restrict__ p, int n) {
  int i = blockIdx.x * 256 + threadIdx.x;
  if (i < n) p[i] = 0.f;
}

// W[k][col] (col = g*512 + j) -> Wp[k][4j+g]; also used for bias (n=2048)
__global__ __launch_bounds__(256) void k_rearr_W(const float* __restrict__ src,
                                                 float* __restrict__ dst, int n) {
  int idx = blockIdx.x * 256 + threadIdx.x;
  if (idx >= n) return;
  int k = idx >> 11, col = idx & 2047;
  int j = col & 511, g = col >> 9;
  dst[k * NR + j * 4 + g] = src[idx];
}

// U[k][col] -> Ucp[jb2][k][ (j&3)*4 + g ]   (jb2 = j>>2; 128 slices of [512][16])
__global__ __launch_bounds__(256) void k_rearr_U(const float* __restrict__ src,
                                                 float* __restrict__ dst) {
  int idx = blockIdx.x * 256 + threadIdx.x;   // over 512*2048
  int k = idx >> 11, col = idx & 2047;
  int j = col & 511, g = col >> 9;
  dst[(size_t)(j >> 2) * 8192 + k * 16 + (j & 3) * 4 + g] = src[idx];
}

// ---------------- projection GEMM ----------------
// xz[tl][r0..r0+64][b] = in_t @ Wp + bp; 64-row tiles (grid 32 x TC -> 2 blocks/CU),
// register-prefetch double-buffered LDS staging to hide global load latency.
// MODE 0: input = x[b][t][f] (layer 1, KD=128). MODE 1: input = seq[t][k][b] (KD=512).
template <int MODE, int KD>
__global__ __launch_bounds__(256) void k_proj(const float* __restrict__ in,
                                              const float* __restrict__ Wp,
                                              const float* __restrict__ bp,
                                              float* __restrict__ xz, int t0) {
  __shared__ float Wt[16 * 68];    // [k][64r] pad->68 (16B-aligned stride)
  __shared__ float Xs[16 * 132];   // [k][128b] pad->132
  int tid = threadIdx.x;
  int r0 = blockIdx.x * 64;
  int tl = blockIdx.y;
  int ty = tid >> 5, tx = tid & 31;   // thread tile: 8 rows x 4 cols
  float acc[8][4];
#pragma unroll
  for (int i = 0; i < 8; ++i)
#pragma unroll
    for (int j = 0; j < 4; ++j) acc[i][j] = 0.f;

  // staging decode
  int wi = (tid * 4) >> 6, wr = (tid * 4) & 63;          // W: 1 float4/thread
  int xi = (tid * 8) >> 7, xb = (tid * 8) & 127;          // X MODE1: 2 float4/thread
  int bb0 = tid >> 1, half0 = tid & 1;                    // X MODE0 scheme

  float4 wreg, xreg0, xreg1;
  // prefetch chunk 0
  {
    wreg = *(const float4*)(Wp + (size_t)(0 + wi) * NR + r0 + wr);
    if (MODE == 1) {
      const float* src = in + (size_t)tl * HB + (size_t)(0 + xi) * BB + xb;
      xreg0 = *(const float4*)(src);
      xreg1 = *(const float4*)(src + 4);
    } else {
      const float* src = in + (size_t)bb0 * (TT * FF) + (size_t)(t0 + tl) * FF + 0 + half0 * 8;
      xreg0 = *(const float4*)(src);
      xreg1 = *(const float4*)(src + 4);
    }
  }

  for (int k0 = 0; k0 < KD; k0 += 16) {
    __syncthreads();   // protect LDS from previous iteration's readers
    *(float4*)&Wt[wi * 68 + wr] = wreg;
    if (MODE == 1) {
      *(float4*)&Xs[xi * 132 + xb] = xreg0;
      *(float4*)&Xs[xi * 132 + xb + 4] = xreg1;
    } else {
#pragma unroll
      for (int q = 0; q < 4; ++q) Xs[(half0 * 8 + q) * 132 + bb0] = (&xreg0.x)[q];
#pragma unroll
      for (int q = 0; q < 4; ++q) Xs[(half0 * 8 + 4 + q) * 132 + bb0] = (&xreg1.x)[q];
    }
    __syncthreads();
    // prefetch next chunk into regs (overlaps with compute below)
    if (k0 + 16 < KD) {
      wreg = *(const float4*)(Wp + (size_t)(k0 + 16 + wi) * NR + r0 + wr);
      if (MODE == 1) {
        const float* src = in + (size_t)tl * HB + (size_t)(k0 + 16 + xi) * BB + xb;
        xreg0 = *(const float4*)(src);
        xreg1 = *(const float4*)(src + 4);
      } else {
        const float* src = in + (size_t)bb0 * (TT * FF) + (size_t)(t0 + tl) * FF + k0 + 16 + half0 * 8;
        xreg0 = *(const float4*)(src);
        xreg1 = *(const float4*)(src + 4);
      }
    }
#pragma unroll
    for (int k = 0; k < 16; ++k) {
      float4 wA = *(const float4*)&Wt[k * 68 + ty * 8];
      float4 wB = *(const float4*)&Wt[k * 68 + ty * 8 + 4];
      float4 xA = *(const float4*)&Xs[k * 132 + tx * 4];
      float w[8] = {wA.x, wA.y, wA.z, wA.w, wB.x, wB.y, wB.z, wB.w};
      float xv[4] = {xA.x, xA.y, xA.z, xA.w};
#pragma unroll
      for (int i = 0; i < 8; ++i)
#pragma unroll
        for (int j = 0; j < 4; ++j) acc[i][j] = fmaf(w[i], xv[j], acc[i][j]);
    }
  }
#pragma unroll
  for (int i = 0; i < 8; ++i) {
    float bv = bp[r0 + ty * 8 + i];
    float* dst = xz + ((size_t)tl * NR + r0 + ty * 8 + i) * BB + tx * 4;
    float4 o = {acc[i][0] + bv, acc[i][1] + bv, acc[i][2] + bv, acc[i][3] + bv};
    *(float4*)(dst) = o;
  }
}

// ---------------- persistent recurrent kernel (TC steps, dataflow-synced) ----------------
// Grid 256 x 1024 (forced 1 block/CU via >80KB LDS). Block bx = jb2*2+bh: jb2 owns
// gate rows jb2*16..+15 (j = jb2*4..+3), bh owns batch half. Per-block flags hold
// completed-step counts (monotone, >= targets; replay-safe). Wave kq consumes h rows
// [32kq,32kq+32) produced by blocks jb2p=8kq..8kq+7 (same bh); it polls exactly
// those 8 flags. h published via relaxed agent atomic stores (write-through L3,
// drained by the pre-flag __syncthreads vmcnt(0)); consumed via relaxed agent
// atomic loads (bypass stale L1/L2). A compiler memory barrier after the poll
// prevents hoisting of the h loads above it (the R6 race).
__global__ __launch_bounds__(1024) void k_rec(const float* __restrict__ Ucp,
                                              const float* __restrict__ xz,
                                              const float* __restrict__ hin0,
                                              float* __restrict__ hchain,
                                              float* __restrict__ cT,
                                              int* __restrict__ flags,
                                              int base) {
  __shared__ float red[20 * 1024];  // [kq][r][b64] (16K used; padded >80KB total LDS)
  __shared__ float zs[1024];        // [r][b64]
  int tid = threadIdx.x;
  int b = tid & 63;
  int kq = tid >> 6;
  int jb2 = blockIdx.x >> 1;
  int bh = blockIdx.x & 1;
  int bg = bh * 64 + b;
  int kqu = __builtin_amdgcn_readfirstlane(kq);
  const float* __restrict__ uk = Ucp + (size_t)jb2 * 8192 + kqu * 32 * 16;  // [32 k][16 r]
  int fidx = (((kqu * 8 + (b & 7)) << 1) | bh) * FLS;   // producer flag (lane-cycled)

  float c_reg = 0.f;
  int jj = tid >> 6;                 // tail threads (tid<256): jj 0..3
  int jg = jb2 * 4 + jj;
  if (tid < 256) c_reg = cT[jg * BB + bg];

  for (int s = 0; s < TC; ++s) {
    // xz prefetch: independent of h -> issue before the poll
    float xzv = xz[((size_t)s * NR + jb2 * 16 + kq) * BB + bg];
    // dataflow wait: my 8 producers must have completed `base+s` steps
    {
      int tgt = base + s;
      while (true) {
        int f = __hip_atomic_load(&flags[fidx], __ATOMIC_RELAXED, __HIP_MEMORY_SCOPE_AGENT);
        if (__all(f >= tgt)) break;
      }
    }
    asm volatile("" ::: "memory");   // compiler barrier: h loads must not hoist above poll
    const float* __restrict__ h = (s == 0) ? hin0 : (hchain + (size_t)(s - 1) * HB);
    const float* __restrict__ hb = h + bg;
    int kbase = kqu * 32;
    float hv[32];
#pragma unroll
    for (int u = 0; u < 32; ++u)
      hv[u] = __hip_atomic_load(&hb[(kbase + u) * BB],
                                __ATOMIC_RELAXED, __HIP_MEMORY_SCOPE_AGENT);
    float acc[16];
#pragma unroll
    for (int r = 0; r < 16; ++r) acc[r] = 0.f;
#pragma unroll
    for (int u = 0; u < 32; ++u) {
      const float* uu = uk + u * 16;
#pragma unroll
      for (int r = 0; r < 16; ++r) acc[r] = fmaf(hv[u], uu[r], acc[r]);
    }
#pragma unroll
    for (int r = 0; r < 16; ++r) red[kq * 1024 + r * 64 + b] = acc[r];
    __syncthreads();
    {
      int r2 = kq;  // wave id doubles as row id
      float z = red[r2 * 64 + b];
#pragma unroll
      for (int q = 1; q < 16; ++q) z += red[q * 1024 + r2 * 64 + b];
      zs[r2 * 64 + b] = z + xzv;
    }
    __syncthreads();
    if (tid < 256) {
      float z0 = zs[(jj * 4 + 0) * 64 + b];
      float z1 = zs[(jj * 4 + 1) * 64 + b];
      float z2 = zs[(jj * 4 + 2) * 64 + b];
      float z3 = zs[(jj * 4 + 3) * 64 + b];
      float igt = 1.f / (1.f + __expf(-z0));
      float fgt = 1.f / (1.f + __expf(-z1));
      float ggt = tanhf(z2);
      float ogt = 1.f / (1.f + __expf(-z3));
      c_reg = fgt * c_reg + igt * ggt;
      float hn = ogt * tanhf(c_reg);
      __hip_atomic_store(&hchain[(size_t)s * HB + jg * BB + bg], hn,
                         __ATOMIC_RELAXED, __HIP_MEMORY_SCOPE_AGENT);
    }
    __syncthreads();  // drains waves 0-3 h stores (vmcnt0) before the flag
    if (tid == 0)
      __hip_atomic_store(&flags[blockIdx.x * FLS], base + s + 1,
                         __ATOMIC_RELAXED, __HIP_MEMORY_SCOPE_AGENT);
  }
  if (tid < 256) cT[jg * BB + bg] = c_reg;
}

// ---------------- dense + softmax ----------------
__global__ __launch_bounds__(64) void k_dense(const float* __restrict__ h2,
                                              const float* __restrict__ Wd,
                                              const float* __restrict__ bd,
                                              float* __restrict__ out) {
  int b = blockIdx.x * 64 + threadIdx.x;
  float acc[10];
#pragma unroll
  for (int c = 0; c < 10; ++c) acc[c] = bd[c];
  for (int k = 0; k < HH; ++k) {
    float hv = h2[k * BB + b];
#pragma unroll
    for (int c = 0; c < 10; ++c) acc[c] = fmaf(hv, Wd[k * 10 + c], acc[c]);
  }
  float m = acc[0];
#pragma unroll
  for (int c = 1; c < 10; ++c) m = fmaxf(m, acc[c]);
  float s = 0.f;
#pragma unroll
  for (int c = 0; c < 10; ++c) { acc[c] = __expf(acc[c] - m); s += acc[c]; }
  float inv = 1.f / s;
#pragma unroll
  for (int c = 0; c < 10; ++c) out[b * 10 + c] = acc[c] * inv;
}

// ---------------- host ----------------
extern "C" void kernel_launch(void* const* d_in, const int* in_sizes, int n_in,
                              void* d_out, int out_size, void* d_ws, size_t ws_size,
                              hipStream_t stream) {
  const float* x  = (const float*)d_in[0];
  const float* W1 = (const float*)d_in[1];
  const float* U1 = (const float*)d_in[2];
  const float* b1 = (const float*)d_in[3];
  const float* W2 = (const float*)d_in[4];
  const float* U2 = (const float*)d_in[5];
  const float* b2 = (const float*)d_in[6];
  const float* Wd = (const float*)d_in[7];
  const float* bd = (const float*)d_in[8];
  float* out = (float*)d_out;

  float* ws  = (float*)d_ws;
  float* seq = ws;                               // [512][512][128]  33,554,432
  float* xz  = seq + (size_t)TT * HB;            // [16][2048][128]   4,194,304
  float* Ucp = xz + (size_t)TC * NR * BB;        // [128][512][16]    1,048,576
  float* Wp1 = Ucp + (size_t)HH * NR;            //   262,144
  float* Wp2 = Wp1 + (size_t)FF * NR;            // 1,048,576
  float* bp1 = Wp2 + (size_t)HH * NR;            //     2,048
  float* bp2 = bp1 + NR;                         //     2,048
  float* hR  = bp2 + NR;                         // [16][65536]       1,048,576
  float* cT  = hR + (size_t)TC * HB;             //    65,536
  int*   flags = (int*)(cT + HB);                //  256*FLS ints (padded 64B/flag)
  // total ~41.2M floats ~165 MB (same footprint as R5/R6)

  // prep
  k_zero<<<(HB + 255) / 256, 256, 0, stream>>>(cT, HB);
  k_zero<<<(HB + 255) / 256, 256, 0, stream>>>(hR, HB);          // hR[0] = layer-1 h0 = 0
  k_zero<<<(256 * FLS) / 256, 256, 0, stream>>>((float*)flags, 256 * FLS);
  k_rearr_W<<<(FF * NR) / 256, 256, 0, stream>>>(W1, Wp1, FF * NR);
  k_rearr_W<<<(HH * NR) / 256, 256, 0, stream>>>(W2, Wp2, HH * NR);
  k_rearr_W<<<NR / 256, 256, 0, stream>>>(b1, bp1, NR);
  k_rearr_W<<<NR / 256, 256, 0, stream>>>(b2, bp2, NR);
  k_rearr_U<<<(HH * NR) / 256, 256, 0, stream>>>(U1, Ucp);

  // layer 1: h chain lives in seq[t] (globally fresh slots)
  for (int c = 0; c < TT / TC; ++c) {
    int t0 = c * TC;
    k_proj<0, FF><<<dim3(NR / 64, TC), 256, 0, stream>>>(x, Wp1, bp1, xz, t0);
    const float* hin0 = (c == 0) ? hR : (seq + (size_t)(t0 - 1) * HB);
    k_rec<<<256, 1024, 0, stream>>>(Ucp, xz, hin0, seq + (size_t)t0 * HB, cT,
                                    flags, t0);
  }
  // swap U buffer to layer 2
  k_rearr_U<<<(HH * NR) / 256, 256, 0, stream>>>(U2, Ucp);
  // layer 2: h chain in hR ring (fresh slot per step within a launch;
  // cross-launch reuse safe because h reads bypass L1/L2)
  for (int c = 0; c < TT / TC; ++c) {
    int t0 = c * TC;
    k_proj<1, HH><<<dim3(NR / 64, TC), 256, 0, stream>>>(seq + (size_t)t0 * HB,
                                                         Wp2, bp2, xz, t0);
    const float* hin0 = (c == 0) ? (seq + (size_t)(TT - 1) * HB)
                                 : (hR + (size_t)(TC - 1) * HB);
    k_rec<<<256, 1024, 0, stream>>>(Ucp, xz, hin0, hR, cT, flags, TT + t0);
  }
  k_dense<<<BB / 64, 64, 0, stream>>>(hR + (size_t)(TC - 1) * HB, Wd, bd, out);
}

// Round 8
// 7667.426 us; speedup vs baseline: 3.9479x; 1.2975x over previous
//
#include <hip/hip_runtime.h>
#include <math.h>

#define BB 128
#define TT 512
#define FF 128
#define HH 512
#define NR 2048      // gate rows, row = 4*j + g
#define TC 16        // timesteps per rec launch
#define HB (HH*BB)   // 65536 elements per h state / c state / xz-quarter
#define FLS 16       // flag stride (ints) -> one flag per 64B line

typedef __attribute__((ext_vector_type(8))) short short8;   // 8 bf16 (A/B frag)
typedef __attribute__((ext_vector_type(4))) float f32x4;    // MFMA C/D frag
typedef unsigned int uint;
typedef unsigned short ushort;

__device__ __forceinline__ ushort f2bf(float f) {           // fp32 -> bf16 RNE
  uint u = __float_as_uint(f);
  u += 0x7fff + ((u >> 16) & 1);
  return (ushort)(u >> 16);
}

// ---------------- prep kernels ----------------

__global__ __launch_bounds__(256) void k_zero(float* __restrict__ p, int n) {
  int i = blockIdx.x * 256 + threadIdx.x;
  if (i < n) p[i] = 0.f;
}

// W[k][col] (col = g*512 + j) -> Wp[k][4j+g]; also used for bias (n=2048)
__global__ __launch_bounds__(256) void k_rearr_W(const float* __restrict__ src,
                                                 float* __restrict__ dst, int n) {
  int idx = blockIdx.x * 256 + threadIdx.x;
  if (idx >= n) return;
  int k = idx >> 11, col = idx & 2047;
  int j = col & 511, g = col >> 9;
  dst[k * NR + j * 4 + g] = src[idx];
}

// U[k][col] -> A-fragment order, bf16 hi/lo split.
// Upk[((jb*16 + kt)*64 + L)*16 + term*8 + j8]:
//   k = kt*32 + (L>>4)*8 + j8 ; m = L&15 ; r = jb*16+m ; j = r>>2 ; g = r&3
__global__ __launch_bounds__(256) void k_pack_U(const float* __restrict__ src,
                                                ushort* __restrict__ dst) {
  int idx = blockIdx.x * 256 + threadIdx.x;   // over 128*16*64*8 = 1048576
  int j8 = idx & 7;
  int L = (idx >> 3) & 63;
  int kt = (idx >> 9) & 15;
  int jb = idx >> 13;
  int k = kt * 32 + (L >> 4) * 8 + j8;
  int m = L & 15;
  int j = jb * 4 + (m >> 2);
  int g = m & 3;
  float v = src[k * NR + g * HH + j];
  ushort hi = f2bf(v);
  float fhi = __uint_as_float(((uint)hi) << 16);
  ushort lo = f2bf(v - fhi);
  size_t base = ((size_t)(jb * 16 + kt) * 64 + L) * 16;
  dst[base + j8] = hi;
  dst[base + 8 + j8] = lo;
}

// ---------------- projection GEMM ----------------
// Computes z_x for 64 gate rows x 128 batch, one t per blockIdx.y.
// Epilogue writes xz4[tl][j][b] = float4(i,f,g,o) (gate-packed per j).
// MODE 0: input = x[b][t][f] fp32 (layer 1, KD=128).
// MODE 1: input = packed-bf16x2 h words [t][k][b] (layer 2, KD=512).
template <int MODE, int KD>
__global__ __launch_bounds__(256) void k_proj(const void* __restrict__ in_,
                                              const float* __restrict__ Wp,
                                              const float* __restrict__ bp,
                                              float4* __restrict__ xz4, int t0) {
  __shared__ float Wt[16 * 68];    // [k][64r] pad->68
  __shared__ float Xs[16 * 132];   // [k][128b] pad->132
  int tid = threadIdx.x;
  int r0 = blockIdx.x * 64;
  int tl = blockIdx.y;
  int ty = tid >> 5, tx = tid & 31;   // thread tile: 8 rows x 4 cols
  float acc[8][4];
#pragma unroll
  for (int i = 0; i < 8; ++i)
#pragma unroll
    for (int j = 0; j < 4; ++j) acc[i][j] = 0.f;

  int wi = (tid * 4) >> 6, wr = (tid * 4) & 63;           // W: 1 float4/thread
  int xi = (tid * 8) >> 7, xb = (tid * 8) & 127;          // X MODE1: 8 words/thread
  int bb0 = tid >> 1, half0 = tid & 1;                    // X MODE0 scheme

  const float* inf = (const float*)in_;
  const uint* inw = (const uint*)in_;

  float4 wreg;
  float xf[8];
  // prefetch chunk 0
  {
    wreg = *(const float4*)(Wp + (size_t)(0 + wi) * NR + r0 + wr);
    if (MODE == 1) {
      const uint* src = inw + (size_t)tl * HB + (size_t)(0 + xi) * BB + xb;
      uint4 v0 = *(const uint4*)(src);
      uint4 v1 = *(const uint4*)(src + 4);
      uint wv[8] = {v0.x, v0.y, v0.z, v0.w, v1.x, v1.y, v1.z, v1.w};
#pragma unroll
      for (int q = 0; q < 8; ++q)
        xf[q] = __uint_as_float(wv[q] & 0xffff0000u) + __uint_as_float(wv[q] << 16);
    } else {
      const float* src = inf + (size_t)bb0 * (TT * FF) + (size_t)(t0 + tl) * FF + half0 * 8;
      float4 v0 = *(const float4*)(src);
      float4 v1 = *(const float4*)(src + 4);
      xf[0]=v0.x; xf[1]=v0.y; xf[2]=v0.z; xf[3]=v0.w;
      xf[4]=v1.x; xf[5]=v1.y; xf[6]=v1.z; xf[7]=v1.w;
    }
  }

  for (int k0 = 0; k0 < KD; k0 += 16) {
    __syncthreads();
    *(float4*)&Wt[wi * 68 + wr] = wreg;
    if (MODE == 1) {
#pragma unroll
      for (int q = 0; q < 8; ++q) Xs[xi * 132 + xb + q] = xf[q];
    } else {
#pragma unroll
      for (int q = 0; q < 8; ++q) Xs[(half0 * 8 + q) * 132 + bb0] = xf[q];
    }
    __syncthreads();
    if (k0 + 16 < KD) {
      wreg = *(const float4*)(Wp + (size_t)(k0 + 16 + wi) * NR + r0 + wr);
      if (MODE == 1) {
        const uint* src = inw + (size_t)tl * HB + (size_t)(k0 + 16 + xi) * BB + xb;
        uint4 v0 = *(const uint4*)(src);
        uint4 v1 = *(const uint4*)(src + 4);
        uint wv[8] = {v0.x, v0.y, v0.z, v0.w, v1.x, v1.y, v1.z, v1.w};
#pragma unroll
        for (int q = 0; q < 8; ++q)
          xf[q] = __uint_as_float(wv[q] & 0xffff0000u) + __uint_as_float(wv[q] << 16);
      } else {
        const float* src = inf + (size_t)bb0 * (TT * FF) + (size_t)(t0 + tl) * FF + k0 + 16 + half0 * 8;
        float4 v0 = *(const float4*)(src);
        float4 v1 = *(const float4*)(src + 4);
        xf[0]=v0.x; xf[1]=v0.y; xf[2]=v0.z; xf[3]=v0.w;
        xf[4]=v1.x; xf[5]=v1.y; xf[6]=v1.z; xf[7]=v1.w;
      }
    }
#pragma unroll
    for (int k = 0; k < 16; ++k) {
      float4 wA = *(const float4*)&Wt[k * 68 + ty * 8];
      float4 wB = *(const float4*)&Wt[k * 68 + ty * 8 + 4];
      float4 xA = *(const float4*)&Xs[k * 132 + tx * 4];
      float w[8] = {wA.x, wA.y, wA.z, wA.w, wB.x, wB.y, wB.z, wB.w};
      float xv[4] = {xA.x, xA.y, xA.z, xA.w};
#pragma unroll
      for (int i = 0; i < 8; ++i)
#pragma unroll
        for (int j = 0; j < 4; ++j) acc[i][j] = fmaf(w[i], xv[j], acc[i][j]);
    }
  }
  // epilogue: gate-packed float4 per (j, col)
#pragma unroll
  for (int jj = 0; jj < 2; ++jj) {
    int j = (r0 >> 2) + ty * 2 + jj;
    float bv0 = bp[r0 + ty * 8 + jj * 4 + 0];
    float bv1 = bp[r0 + ty * 8 + jj * 4 + 1];
    float bv2 = bp[r0 + ty * 8 + jj * 4 + 2];
    float bv3 = bp[r0 + ty * 8 + jj * 4 + 3];
#pragma unroll
    for (int c = 0; c < 4; ++c) {
      float4 o = {acc[jj * 4 + 0][c] + bv0, acc[jj * 4 + 1][c] + bv1,
                  acc[jj * 4 + 2][c] + bv2, acc[jj * 4 + 3][c] + bv3};
      xz4[((size_t)tl * HH + j) * BB + tx * 4 + c] = o;
    }
  }
}

// ---------------- persistent recurrent kernel (MFMA, TC steps, dataflow-synced) --------
// Grid 256 x 256 (all blocks resident). Block bx = jb*2+bh: jb (0..127) owns the
// 16 gate rows jb*16..+15 (j = jb*4..+3); bh owns batch half (64 cols).
// 4 waves = 4 col-tiles of 16. MFMA 16x16x32_bf16, 3-term bf16 split:
// D = Uhi*hhi + Ulo*hhi + Uhi*hlo (lo*lo skipped, ~2^-17 rel).
// U frags live in REGISTERS (loaded once/launch). h transported as packed
// bf16 hi|lo in one u32 (same bytes as fp32). C/D layout: lane(q=L>>4,n=L&15)
// holds rows q*4+0..3 = the 4 gates of j=jb*4+q, col n -> gate tail is
// lane-local: NO LDS at all. Dataflow flags as in R7 (relaxed, monotone, >=).
__global__ __launch_bounds__(256, 1) void k_rec(const ushort* __restrict__ Upk,
                                                const float4* __restrict__ xz4,
                                                const uint* __restrict__ hin0,
                                                uint* __restrict__ hchain,
                                                float* __restrict__ cT,
                                                int* __restrict__ flags,
                                                int base) {
  int tid = threadIdx.x;
  int L = tid & 63;
  int ct = tid >> 6;            // wave id = col tile
  int jb = blockIdx.x >> 1;
  int bh = blockIdx.x & 1;
  int q = L >> 4, n = L & 15;
  int col = bh * 64 + ct * 16 + n;
  int j = jb * 4 + q;           // this lane's hidden unit (tail)
  int hrow = q * 8;             // B-frag k-offset within a 32-k tile

  // U fragments: 16 kt x (hi,lo) = 128 VGPRs, loaded once
  short8 uh[16], ul[16];
  {
    const ushort* ub = Upk + ((size_t)(jb * 16) * 64 + L) * 16;
#pragma unroll
    for (int kt = 0; kt < 16; ++kt) {
      uh[kt] = *(const short8*)(ub + (size_t)kt * 1024);
      ul[kt] = *(const short8*)(ub + (size_t)kt * 1024 + 8);
    }
  }
  float c_reg = cT[j * BB + col];
  int fi0 = (bh * 128 + L) * FLS;
  int fi1 = (bh * 128 + 64 + L) * FLS;

  for (int s = 0; s < TC; ++s) {
    // xz prefetch (stable memory) before the poll
    float4 xzv = xz4[((size_t)s * HH + j) * BB + col];
    int tgt = base + s;
    while (true) {
      int f0 = __hip_atomic_load(&flags[fi0], __ATOMIC_RELAXED, __HIP_MEMORY_SCOPE_AGENT);
      int f1 = __hip_atomic_load(&flags[fi1], __ATOMIC_RELAXED, __HIP_MEMORY_SCOPE_AGENT);
      if (__all((f0 >= tgt) && (f1 >= tgt))) break;
    }
    asm volatile("" ::: "memory");   // h loads must not hoist above the poll
    const uint* __restrict__ h = (s == 0) ? hin0 : (hchain + (size_t)(s - 1) * HB);
    const uint* __restrict__ hc = h + col;

    f32x4 a0 = {0.f, 0.f, 0.f, 0.f};
    f32x4 a1 = {0.f, 0.f, 0.f, 0.f};
    f32x4 a2 = {0.f, 0.f, 0.f, 0.f};
    uint w[8], wn[8];
#pragma unroll
    for (int u = 0; u < 8; ++u)
      w[u] = __hip_atomic_load(&hc[(hrow + u) * BB], __ATOMIC_RELAXED, __HIP_MEMORY_SCOPE_AGENT);
#pragma unroll
    for (int kt = 0; kt < 16; ++kt) {
      if (kt < 15) {
#pragma unroll
        for (int u = 0; u < 8; ++u)
          wn[u] = __hip_atomic_load(&hc[((kt + 1) * 32 + hrow + u) * BB],
                                    __ATOMIC_RELAXED, __HIP_MEMORY_SCOPE_AGENT);
      }
      short8 bhi, blo;
#pragma unroll
      for (int u = 0; u < 8; ++u) {
        bhi[u] = (short)(w[u] >> 16);
        blo[u] = (short)(w[u] & 0xffffu);
      }
      a0 = __builtin_amdgcn_mfma_f32_16x16x32_bf16(uh[kt], bhi, a0, 0, 0, 0);
      a1 = __builtin_amdgcn_mfma_f32_16x16x32_bf16(ul[kt], bhi, a1, 0, 0, 0);
      a2 = __builtin_amdgcn_mfma_f32_16x16x32_bf16(uh[kt], blo, a2, 0, 0, 0);
      if (kt < 15) {
#pragma unroll
        for (int u = 0; u < 8; ++u) w[u] = wn[u];
      }
    }
    // tail: lane owns gates i,f,g,o of (j, col) in a*.x..w
    float z0 = a0.x + a1.x + a2.x + xzv.x;
    float z1 = a0.y + a1.y + a2.y + xzv.y;
    float z2 = a0.z + a1.z + a2.z + xzv.z;
    float z3 = a0.w + a1.w + a2.w + xzv.w;
    float ig = 1.f / (1.f + __expf(-z0));
    float fg = 1.f / (1.f + __expf(-z1));
    float gg = tanhf(z2);
    float og = 1.f / (1.f + __expf(-z3));
    c_reg = fg * c_reg + ig * gg;
    float hn = og * tanhf(c_reg);
    ushort hi = f2bf(hn);
    float fhi = __uint_as_float(((uint)hi) << 16);
    ushort lo = f2bf(hn - fhi);
    uint word = (((uint)hi) << 16) | (uint)lo;
    __hip_atomic_store(&hchain[(size_t)s * HB + j * BB + col], word,
                       __ATOMIC_RELAXED, __HIP_MEMORY_SCOPE_AGENT);
    __syncthreads();   // drain all 4 waves' h stores (vmcnt0) before the flag
    if (tid == 0)
      __hip_atomic_store(&flags[(bh * 128 + jb) * FLS], base + s + 1,
                         __ATOMIC_RELAXED, __HIP_MEMORY_SCOPE_AGENT);
  }
  cT[j * BB + col] = c_reg;
}

// ---------------- dense + softmax ----------------
__global__ __launch_bounds__(64) void k_dense(const uint* __restrict__ h2,
                                              const float* __restrict__ Wd,
                                              const float* __restrict__ bd,
                                              float* __restrict__ out) {
  int b = blockIdx.x * 64 + threadIdx.x;
  float acc[10];
#pragma unroll
  for (int c = 0; c < 10; ++c) acc[c] = bd[c];
  for (int k = 0; k < HH; ++k) {
    uint w = h2[k * BB + b];
    float hv = __uint_as_float(w & 0xffff0000u) + __uint_as_float(w << 16);
#pragma unroll
    for (int c = 0; c < 10; ++c) acc[c] = fmaf(hv, Wd[k * 10 + c], acc[c]);
  }
  float m = acc[0];
#pragma unroll
  for (int c = 1; c < 10; ++c) m = fmaxf(m, acc[c]);
  float s = 0.f;
#pragma unroll
  for (int c = 0; c < 10; ++c) { acc[c] = __expf(acc[c] - m); s += acc[c]; }
  float inv = 1.f / s;
#pragma unroll
  for (int c = 0; c < 10; ++c) out[b * 10 + c] = acc[c] * inv;
}

// ---------------- host ----------------
extern "C" void kernel_launch(void* const* d_in, const int* in_sizes, int n_in,
                              void* d_out, int out_size, void* d_ws, size_t ws_size,
                              hipStream_t stream) {
  const float* x  = (const float*)d_in[0];
  const float* W1 = (const float*)d_in[1];
  const float* U1 = (const float*)d_in[2];
  const float* b1 = (const float*)d_in[3];
  const float* W2 = (const float*)d_in[4];
  const float* U2 = (const float*)d_in[5];
  const float* b2 = (const float*)d_in[6];
  const float* Wd = (const float*)d_in[7];
  const float* bd = (const float*)d_in[8];
  float* out = (float*)d_out;

  // layout (4-byte units)
  uint*   seq  = (uint*)d_ws;                       // [512][HB] packed h  33,554,432
  float4* xz4  = (float4*)(seq + (size_t)TT * HB);  // [16][512][128] f4    4,194,304 f
  float*  Wp1  = (float*)(xz4 + (size_t)TC * HH * BB);   //    262,144
  float*  Wp2  = Wp1 + (size_t)FF * NR;             //  1,048,576
  float*  bp1  = Wp2 + (size_t)HH * NR;             //      2,048
  float*  bp2  = bp1 + NR;                          //      2,048
  ushort* Up1  = (ushort*)(bp2 + NR);               //  2,097,152 shorts (1,048,576 u)
  ushort* Up2  = Up1 + (size_t)2097152;             //  2,097,152 shorts
  uint*   hR   = (uint*)(Up2 + (size_t)2097152);    // [16][HB] ring       1,048,576
  float*  cT   = (float*)(hR + (size_t)TC * HB);    //     65,536
  int*    flags = (int*)(cT + HB);                  //  256*FLS ints
  // total ~42.4M 4B-units ~170 MB (R3 proved 181 MB fits)

  // prep
  k_zero<<<(HB + 255) / 256, 256, 0, stream>>>(cT, HB);
  k_zero<<<(HB + 255) / 256, 256, 0, stream>>>((float*)hR, HB);  // hR[0] = h0 = 0
  k_zero<<<(256 * FLS) / 256, 256, 0, stream>>>((float*)flags, 256 * FLS);
  k_rearr_W<<<(FF * NR) / 256, 256, 0, stream>>>(W1, Wp1, FF * NR);
  k_rearr_W<<<(HH * NR) / 256, 256, 0, stream>>>(W2, Wp2, HH * NR);
  k_rearr_W<<<NR / 256, 256, 0, stream>>>(b1, bp1, NR);
  k_rearr_W<<<NR / 256, 256, 0, stream>>>(b2, bp2, NR);
  k_pack_U<<<4096, 256, 0, stream>>>(U1, Up1);
  k_pack_U<<<4096, 256, 0, stream>>>(U2, Up2);

  // layer 1: h chain lives in seq[t]
  for (int c = 0; c < TT / TC; ++c) {
    int t0 = c * TC;
    k_proj<0, FF><<<dim3(NR / 64, TC), 256, 0, stream>>>(x, Wp1, bp1, xz4, t0);
    const uint* hin0 = (c == 0) ? hR : (seq + (size_t)(t0 - 1) * HB);
    k_rec<<<256, 256, 0, stream>>>(Up1, xz4, hin0, seq + (size_t)t0 * HB, cT,
                                   flags, t0);
  }
  // layer 2: h chain in hR ring
  for (int c = 0; c < TT / TC; ++c) {
    int t0 = c * TC;
    k_proj<1, HH><<<dim3(NR / 64, TC), 256, 0, stream>>>(seq + (size_t)t0 * HB,
                                                         Wp2, bp2, xz4, t0);
    const uint* hin0 = (c == 0) ? (seq + (size_t)(TT - 1) * HB)
                                : (hR + (size_t)(TC - 1) * HB);
    k_rec<<<256, 256, 0, stream>>>(Up2, xz4, hin0, hR, cT, flags, TT + t0);
  }
  k_dense<<<BB / 64, 64, 0, stream>>>(hR + (size_t)(TC - 1) * HB, Wd, bd, out);
}

// Round 9
// 6794.930 us; speedup vs baseline: 4.4548x; 1.1284x over previous
//
#include <hip/hip_runtime.h>
#include <math.h>

#define BB 128
#define TT 512
#define FF 128
#define HH 512
#define NR 2048      // gate rows, row = 4*j + g
#define TC 16        // timesteps per rec launch
#define HB (HH*BB)   // 65536 elements per h state / c state
#define FLS 16       // flag stride (ints) -> one flag per 64B line

typedef __attribute__((ext_vector_type(8))) short short8;   // 8 bf16 (A/B frag)
typedef __attribute__((ext_vector_type(4))) float f32x4;    // MFMA C/D frag
typedef unsigned int uint;
typedef unsigned short ushort;

__device__ __forceinline__ ushort f2bf(float f) {           // fp32 -> bf16 RNE
  uint u = __float_as_uint(f);
  u += 0x7fff + ((u >> 16) & 1);
  return (ushort)(u >> 16);
}

// ---------------- prep kernels ----------------

__global__ __launch_bounds__(256) void k_zero(float* __restrict__ p, int n) {
  int i = blockIdx.x * 256 + threadIdx.x;
  if (i < n) p[i] = 0.f;
}

// W[k][col] (col = g*512 + j) -> Wp[k][4j+g]; also used for bias (n=2048)
__global__ __launch_bounds__(256) void k_rearr_W(const float* __restrict__ src,
                                                 float* __restrict__ dst, int n) {
  int idx = blockIdx.x * 256 + threadIdx.x;
  if (idx >= n) return;
  int k = idx >> 11, col = idx & 2047;
  int j = col & 511, g = col >> 9;
  dst[k * NR + j * 4 + g] = src[idx];
}

// [512][2048] matrix (U or W2) -> A-fragment order, bf16 hi/lo split.
// dst[((jb*16 + kt)*64 + L)*16 + term*8 + j8]:
//   k = kt*32 + (L>>4)*8 + j8 ; m = L&15 ; j = jb*4 + (m>>2) ; g = m&3
__global__ __launch_bounds__(256) void k_pack_U(const float* __restrict__ src,
                                                ushort* __restrict__ dst) {
  int idx = blockIdx.x * 256 + threadIdx.x;   // over 128*16*64*8 = 1048576
  int j8 = idx & 7;
  int L = (idx >> 3) & 63;
  int kt = (idx >> 9) & 15;
  int jb = idx >> 13;
  int k = kt * 32 + (L >> 4) * 8 + j8;
  int m = L & 15;
  int j = jb * 4 + (m >> 2);
  int g = m & 3;
  float v = src[k * NR + g * HH + j];
  ushort hi = f2bf(v);
  float fhi = __uint_as_float(((uint)hi) << 16);
  ushort lo = f2bf(v - fhi);
  size_t base = ((size_t)(jb * 16 + kt) * 64 + L) * 16;
  dst[base + j8] = hi;
  dst[base + 8 + j8] = lo;
}

// ---------------- layer-1 projection GEMM (VALU, fp32 x input) ----------------
// Computes z_x for 64 gate rows x 128 batch, one t per blockIdx.y.
// Epilogue writes xz4[tl][j][b] = float4(i,f,g,o) (gate-packed per j).
__global__ __launch_bounds__(256) void k_proj1(const float* __restrict__ in,
                                               const float* __restrict__ Wp,
                                               const float* __restrict__ bp,
                                               float4* __restrict__ xz4, int t0) {
  __shared__ float Wt[16 * 68];    // [k][64r] pad->68
  __shared__ float Xs[16 * 132];   // [k][128b] pad->132
  int tid = threadIdx.x;
  int r0 = blockIdx.x * 64;
  int tl = blockIdx.y;
  int ty = tid >> 5, tx = tid & 31;   // thread tile: 8 rows x 4 cols
  float acc[8][4];
#pragma unroll
  for (int i = 0; i < 8; ++i)
#pragma unroll
    for (int j = 0; j < 4; ++j) acc[i][j] = 0.f;

  int wi = (tid * 4) >> 6, wr = (tid * 4) & 63;           // W: 1 float4/thread
  int bb0 = tid >> 1, half0 = tid & 1;                    // X scheme

  float4 wreg;
  float xf[8];
  {
    wreg = *(const float4*)(Wp + (size_t)wi * NR + r0 + wr);
    const float* src = in + (size_t)bb0 * (TT * FF) + (size_t)(t0 + tl) * FF + half0 * 8;
    float4 v0 = *(const float4*)(src);
    float4 v1 = *(const float4*)(src + 4);
    xf[0]=v0.x; xf[1]=v0.y; xf[2]=v0.z; xf[3]=v0.w;
    xf[4]=v1.x; xf[5]=v1.y; xf[6]=v1.z; xf[7]=v1.w;
  }

  for (int k0 = 0; k0 < FF; k0 += 16) {
    __syncthreads();
    *(float4*)&Wt[wi * 68 + wr] = wreg;
#pragma unroll
    for (int q = 0; q < 8; ++q) Xs[(half0 * 8 + q) * 132 + bb0] = xf[q];
    __syncthreads();
    if (k0 + 16 < FF) {
      wreg = *(const float4*)(Wp + (size_t)(k0 + 16 + wi) * NR + r0 + wr);
      const float* src = in + (size_t)bb0 * (TT * FF) + (size_t)(t0 + tl) * FF + k0 + 16 + half0 * 8;
      float4 v0 = *(const float4*)(src);
      float4 v1 = *(const float4*)(src + 4);
      xf[0]=v0.x; xf[1]=v0.y; xf[2]=v0.z; xf[3]=v0.w;
      xf[4]=v1.x; xf[5]=v1.y; xf[6]=v1.z; xf[7]=v1.w;
    }
#pragma unroll
    for (int k = 0; k < 16; ++k) {
      float4 wA = *(const float4*)&Wt[k * 68 + ty * 8];
      float4 wB = *(const float4*)&Wt[k * 68 + ty * 8 + 4];
      float4 xA = *(const float4*)&Xs[k * 132 + tx * 4];
      float w[8] = {wA.x, wA.y, wA.z, wA.w, wB.x, wB.y, wB.z, wB.w};
      float xv[4] = {xA.x, xA.y, xA.z, xA.w};
#pragma unroll
      for (int i = 0; i < 8; ++i)
#pragma unroll
        for (int j = 0; j < 4; ++j) acc[i][j] = fmaf(w[i], xv[j], acc[i][j]);
    }
  }
#pragma unroll
  for (int jj = 0; jj < 2; ++jj) {
    int j = (r0 >> 2) + ty * 2 + jj;
    float bv0 = bp[r0 + ty * 8 + jj * 4 + 0];
    float bv1 = bp[r0 + ty * 8 + jj * 4 + 1];
    float bv2 = bp[r0 + ty * 8 + jj * 4 + 2];
    float bv3 = bp[r0 + ty * 8 + jj * 4 + 3];
#pragma unroll
    for (int c = 0; c < 4; ++c) {
      float4 o = {acc[jj * 4 + 0][c] + bv0, acc[jj * 4 + 1][c] + bv1,
                  acc[jj * 4 + 2][c] + bv2, acc[jj * 4 + 3][c] + bv3};
      xz4[((size_t)tl * HH + j) * BB + tx * 4 + c] = o;
    }
  }
}

// ---------------- layer-2 projection GEMM (MFMA, packed-bf16 h input) ----------------
// Grid (32 rb, 16 tl) x 256. Wave w owns 16 gate rows (jbp = rb*4+w), all 128 cols
// as 8 col-tiles of 16x16. Same frag layouts as k_rec (proven R8): A from k_pack_U
// format, B words -> bf16 hi/lo, 3-term split folded into one acc per tile.
// Epilogue: lane (q,n) holds gates i,f,g,o of j=jbp*4+q, col ct*16+n -> float4.
__global__ __launch_bounds__(256) void k_proj2(const uint* __restrict__ hw,
                                               const ushort* __restrict__ Wpk,
                                               const float* __restrict__ bp,
                                               float4* __restrict__ xz4) {
  int tid = threadIdx.x;
  int L = tid & 63;
  int w = tid >> 6;
  int jbp = blockIdx.x * 4 + w;
  int tl = blockIdx.y;
  int q = L >> 4, n = L & 15;
  const uint* hb = hw + (size_t)tl * HB;
  f32x4 acc[8];
#pragma unroll
  for (int ct = 0; ct < 8; ++ct) acc[ct] = (f32x4){0.f, 0.f, 0.f, 0.f};

  for (int kt = 0; kt < 16; ++kt) {
    const ushort* ub = Wpk + ((size_t)(jbp * 16 + kt) * 64 + L) * 16;
    short8 uh = *(const short8*)(ub);
    short8 ul = *(const short8*)(ub + 8);
#pragma unroll
    for (int ct = 0; ct < 8; ++ct) {
      uint wv[8];
#pragma unroll
      for (int u = 0; u < 8; ++u)
        wv[u] = hb[(size_t)(kt * 32 + q * 8 + u) * BB + ct * 16 + n];
      short8 bhi, blo;
#pragma unroll
      for (int u = 0; u < 8; ++u) {
        bhi[u] = (short)(wv[u] >> 16);
        blo[u] = (short)(wv[u] & 0xffffu);
      }
      acc[ct] = __builtin_amdgcn_mfma_f32_16x16x32_bf16(uh, bhi, acc[ct], 0, 0, 0);
      acc[ct] = __builtin_amdgcn_mfma_f32_16x16x32_bf16(ul, bhi, acc[ct], 0, 0, 0);
      acc[ct] = __builtin_amdgcn_mfma_f32_16x16x32_bf16(uh, blo, acc[ct], 0, 0, 0);
    }
  }
  int j = jbp * 4 + q;
  float4 bv = *(const float4*)(bp + j * 4);
#pragma unroll
  for (int ct = 0; ct < 8; ++ct) {
    float4 o = {acc[ct].x + bv.x, acc[ct].y + bv.y, acc[ct].z + bv.z, acc[ct].w + bv.w};
    xz4[((size_t)tl * HH + j) * BB + ct * 16 + n] = o;
  }
}

// ---------------- persistent recurrent kernel (MFMA, TC steps, dataflow-synced) --------
// Grid 256 x 256. Block bx = jb*2+bh: jb owns 16 gate rows (j=jb*4..+3), bh the
// batch half; 4 waves = 4 col-tiles. U frags in registers. h STORES are agent
// write-through (drained before the flag); h LOADS are PLAIN CACHED loads:
// within a launch every h slot address is fresh (never re-written), L1/L2 are
// invalidated at dispatch, and the poll (atomic, L2-bypass) + compiler barrier
// orders the load after the producer's write-through -> no staleness, and the
// ~16 same-XCD consumer blocks share each line via L2 (L3 broadcast -> L2
// broadcast; 32 MB/step L3 traffic -> ~2 MB/step).
__global__ __launch_bounds__(256, 1) void k_rec(const ushort* __restrict__ Upk,
                                                const float4* __restrict__ xz4,
                                                const uint* __restrict__ hin0,
                                                uint* __restrict__ hchain,
                                                float* __restrict__ cT,
                                                int* __restrict__ flags,
                                                int base) {
  int tid = threadIdx.x;
  int L = tid & 63;
  int ct = tid >> 6;            // wave id = col tile
  int jb = blockIdx.x >> 1;
  int bh = blockIdx.x & 1;
  int q = L >> 4, n = L & 15;
  int col = bh * 64 + ct * 16 + n;
  int j = jb * 4 + q;           // this lane's hidden unit (tail)
  int hrow = q * 8;             // B-frag k-offset within a 32-k tile

  // U fragments: 16 kt x (hi,lo) = 128 VGPRs, loaded once
  short8 uh[16], ul[16];
  {
    const ushort* ub = Upk + ((size_t)(jb * 16) * 64 + L) * 16;
#pragma unroll
    for (int kt = 0; kt < 16; ++kt) {
      uh[kt] = *(const short8*)(ub + (size_t)kt * 1024);
      ul[kt] = *(const short8*)(ub + (size_t)kt * 1024 + 8);
    }
  }
  float c_reg = cT[j * BB + col];
  int fi0 = (bh * 128 + L) * FLS;
  int fi1 = (bh * 128 + 64 + L) * FLS;

  for (int s = 0; s < TC; ++s) {
    // xz prefetch (stable memory) before the poll
    float4 xzv = xz4[((size_t)s * HH + j) * BB + col];
    int tgt = base + s;
    while (true) {
      int f0 = __hip_atomic_load(&flags[fi0], __ATOMIC_RELAXED, __HIP_MEMORY_SCOPE_AGENT);
      int f1 = __hip_atomic_load(&flags[fi1], __ATOMIC_RELAXED, __HIP_MEMORY_SCOPE_AGENT);
      if (__all((f0 >= tgt) && (f1 >= tgt))) break;
    }
    asm volatile("" ::: "memory");   // h loads must not hoist above the poll
    const uint* __restrict__ h = (s == 0) ? hin0 : (hchain + (size_t)(s - 1) * HB);
    const uint* __restrict__ hc = h + col;

    f32x4 a0 = {0.f, 0.f, 0.f, 0.f};
    f32x4 a1 = {0.f, 0.f, 0.f, 0.f};
    f32x4 a2 = {0.f, 0.f, 0.f, 0.f};
    uint w[8], wn[8];
#pragma unroll
    for (int u = 0; u < 8; ++u)
      w[u] = hc[(size_t)(hrow + u) * BB];
#pragma unroll
    for (int kt = 0; kt < 16; ++kt) {
      if (kt < 15) {
#pragma unroll
        for (int u = 0; u < 8; ++u)
          wn[u] = hc[(size_t)((kt + 1) * 32 + hrow + u) * BB];
      }
      short8 bhi, blo;
#pragma unroll
      for (int u = 0; u < 8; ++u) {
        bhi[u] = (short)(w[u] >> 16);
        blo[u] = (short)(w[u] & 0xffffu);
      }
      a0 = __builtin_amdgcn_mfma_f32_16x16x32_bf16(uh[kt], bhi, a0, 0, 0, 0);
      a1 = __builtin_amdgcn_mfma_f32_16x16x32_bf16(ul[kt], bhi, a1, 0, 0, 0);
      a2 = __builtin_amdgcn_mfma_f32_16x16x32_bf16(uh[kt], blo, a2, 0, 0, 0);
      if (kt < 15) {
#pragma unroll
        for (int u = 0; u < 8; ++u) w[u] = wn[u];
      }
    }
    float z0 = a0.x + a1.x + a2.x + xzv.x;
    float z1 = a0.y + a1.y + a2.y + xzv.y;
    float z2 = a0.z + a1.z + a2.z + xzv.z;
    float z3 = a0.w + a1.w + a2.w + xzv.w;
    float ig = 1.f / (1.f + __expf(-z0));
    float fg = 1.f / (1.f + __expf(-z1));
    float gg = tanhf(z2);
    float og = 1.f / (1.f + __expf(-z3));
    c_reg = fg * c_reg + ig * gg;
    float hn = og * tanhf(c_reg);
    ushort hi = f2bf(hn);
    float fhi = __uint_as_float(((uint)hi) << 16);
    ushort lo = f2bf(hn - fhi);
    uint word = (((uint)hi) << 16) | (uint)lo;
    __hip_atomic_store(&hchain[(size_t)s * HB + j * BB + col], word,
                       __ATOMIC_RELAXED, __HIP_MEMORY_SCOPE_AGENT);
    __syncthreads();   // drain all 4 waves' h stores (vmcnt0) before the flag
    if (tid == 0)
      __hip_atomic_store(&flags[(bh * 128 + jb) * FLS], base + s + 1,
                         __ATOMIC_RELAXED, __HIP_MEMORY_SCOPE_AGENT);
  }
  cT[j * BB + col] = c_reg;
}

// ---------------- dense + softmax ----------------
__global__ __launch_bounds__(64) void k_dense(const uint* __restrict__ h2,
                                              const float* __restrict__ Wd,
                                              const float* __restrict__ bd,
                                              float* __restrict__ out) {
  int b = blockIdx.x * 64 + threadIdx.x;
  float acc[10];
#pragma unroll
  for (int c = 0; c < 10; ++c) acc[c] = bd[c];
  for (int k = 0; k < HH; ++k) {
    uint w = h2[k * BB + b];
    float hv = __uint_as_float(w & 0xffff0000u) + __uint_as_float(w << 16);
#pragma unroll
    for (int c = 0; c < 10; ++c) acc[c] = fmaf(hv, Wd[k * 10 + c], acc[c]);
  }
  float m = acc[0];
#pragma unroll
  for (int c = 1; c < 10; ++c) m = fmaxf(m, acc[c]);
  float s = 0.f;
#pragma unroll
  for (int c = 0; c < 10; ++c) { acc[c] = __expf(acc[c] - m); s += acc[c]; }
  float inv = 1.f / s;
#pragma unroll
  for (int c = 0; c < 10; ++c) out[b * 10 + c] = acc[c] * inv;
}

// ---------------- host ----------------
extern "C" void kernel_launch(void* const* d_in, const int* in_sizes, int n_in,
                              void* d_out, int out_size, void* d_ws, size_t ws_size,
                              hipStream_t stream) {
  const float* x  = (const float*)d_in[0];
  const float* W1 = (const float*)d_in[1];
  const float* U1 = (const float*)d_in[2];
  const float* b1 = (const float*)d_in[3];
  const float* W2 = (const float*)d_in[4];
  const float* U2 = (const float*)d_in[5];
  const float* b2 = (const float*)d_in[6];
  const float* Wd = (const float*)d_in[7];
  const float* bd = (const float*)d_in[8];
  float* out = (float*)d_out;

  // layout (4-byte units)
  uint*   seq  = (uint*)d_ws;                       // [512][HB] packed h  33,554,432
  float4* xz4  = (float4*)(seq + (size_t)TT * HB);  // [16][512][128] f4    4,194,304 f
  float*  Wp1  = (float*)(xz4 + (size_t)TC * HH * BB);   //    262,144
  float*  bp1  = Wp1 + (size_t)FF * NR;             //      2,048
  float*  bp2  = bp1 + NR;                          //      2,048
  ushort* Up1  = (ushort*)(bp2 + NR);               //  2,097,152 shorts
  ushort* Up2  = Up1 + (size_t)2097152;             //  2,097,152 shorts
  ushort* W2pk = Up2 + (size_t)2097152;             //  2,097,152 shorts
  uint*   hR   = (uint*)(W2pk + (size_t)2097152);   // [16][HB] ring       1,048,576
  float*  cT   = (float*)(hR + (size_t)TC * HB);    //     65,536
  int*    flags = (int*)(cT + HB);                  //  256*FLS ints
  // total ~42.3M 4B-units ~169 MB (<= R3's proven 181 MB)

  // prep
  k_zero<<<(HB + 255) / 256, 256, 0, stream>>>(cT, HB);
  k_zero<<<(HB + 255) / 256, 256, 0, stream>>>((float*)hR, HB);  // hR[0] = h0 = 0
  k_zero<<<(256 * FLS) / 256, 256, 0, stream>>>((float*)flags, 256 * FLS);
  k_rearr_W<<<(FF * NR) / 256, 256, 0, stream>>>(W1, Wp1, FF * NR);
  k_rearr_W<<<NR / 256, 256, 0, stream>>>(b1, bp1, NR);
  k_rearr_W<<<NR / 256, 256, 0, stream>>>(b2, bp2, NR);
  k_pack_U<<<4096, 256, 0, stream>>>(U1, Up1);
  k_pack_U<<<4096, 256, 0, stream>>>(U2, Up2);
  k_pack_U<<<4096, 256, 0, stream>>>(W2, W2pk);

  // layer 1: h chain lives in seq[t]
  for (int c = 0; c < TT / TC; ++c) {
    int t0 = c * TC;
    k_proj1<<<dim3(NR / 64, TC), 256, 0, stream>>>(x, Wp1, bp1, xz4, t0);
    const uint* hin0 = (c == 0) ? hR : (seq + (size_t)(t0 - 1) * HB);
    k_rec<<<256, 256, 0, stream>>>(Up1, xz4, hin0, seq + (size_t)t0 * HB, cT,
                                   flags, t0);
  }
  // layer 2: h chain in hR ring
  for (int c = 0; c < TT / TC; ++c) {
    int t0 = c * TC;
    k_proj2<<<dim3(32, TC), 256, 0, stream>>>(seq + (size_t)t0 * HB,
                                              W2pk, bp2, xz4);
    const uint* hin0 = (c == 0) ? (seq + (size_t)(TT - 1) * HB)
                                : (hR + (size_t)(TC - 1) * HB);
    k_rec<<<256, 256, 0, stream>>>(Up2, xz4, hin0, hR, cT, flags, TT + t0);
  }
  k_dense<<<BB / 64, 64, 0, stream>>>(hR + (size_t)(TC - 1) * HB, Wd, bd, out);
}